// Round 2
// baseline (797.130 us; speedup 1.0000x reference)
//
#include <hip/hip_runtime.h>

// Problem constants (from reference setup_inputs)
constexpr int Bn   = 4;
constexpr int NL   = 1024;
constexpr int HWn  = 4096;
constexpr int CK   = 256;   // == Cval == Cout
constexpr int NH   = 8;
// dk = dv = 32, scale = Ck^-0.5 = 0.0625

__device__ __forceinline__ void load4f(const float* p, float* o) {
  float4 v = *(const float4*)p; o[0] = v.x; o[1] = v.y; o[2] = v.z; o[3] = v.w;
}

// C[m,n] = sum_k A[m,k] * W[n,k] + bias[n]   (NT gemm, f32 accumulate/output)
// grid = (M/64, N/64), block = 256. K % 32 == 0, lda/ldw/ldc % 4 == 0.
__global__ __launch_bounds__(256) void gemm_nt(const float* __restrict__ A, int lda,
    const float* __restrict__ W, int ldw,
    const float* __restrict__ bias,
    float* __restrict__ C, int ldc, int K)
{
  __shared__ float As[32][68];  // [kk][m], 68 keeps rows 16B-aligned, breaks pow2 stride
  __shared__ float Ws[32][68];  // [kk][n]
  const int bm = blockIdx.x * 64, bn = blockIdx.y * 64;
  const int tid = threadIdx.x;
  const int ty = tid >> 4, tx = tid & 15;
  float acc[4][4] = {};

  for (int k0 = 0; k0 < K; k0 += 32) {
#pragma unroll
    for (int it = 0; it < 2; ++it) {
      int c = tid + it * 256;          // 0..511 : 64 rows x 8 vec4-chunks
      int m = c >> 3, kq = (c & 7) << 2;
      float av[4], wv[4];
      load4f(A + (size_t)(bm + m) * lda + k0 + kq, av);
      load4f(W + (size_t)(bn + m) * ldw + k0 + kq, wv);
      As[kq + 0][m] = av[0]; As[kq + 1][m] = av[1]; As[kq + 2][m] = av[2]; As[kq + 3][m] = av[3];
      Ws[kq + 0][m] = wv[0]; Ws[kq + 1][m] = wv[1]; Ws[kq + 2][m] = wv[2]; Ws[kq + 3][m] = wv[3];
    }
    __syncthreads();
#pragma unroll
    for (int kk = 0; kk < 32; ++kk) {
      float a[4], w[4];
      *(float4*)a = *(const float4*)&As[kk][ty << 2];
      *(float4*)w = *(const float4*)&Ws[kk][tx << 2];
#pragma unroll
      for (int i = 0; i < 4; ++i)
#pragma unroll
        for (int j = 0; j < 4; ++j)
          acc[i][j] = fmaf(a[i], w[j], acc[i][j]);
    }
    __syncthreads();
  }

  const int row0 = bm + (ty << 2), col0 = bn + (tx << 2);
  float bb[4];
#pragma unroll
  for (int j = 0; j < 4; ++j) bb[j] = bias[col0 + j];
#pragma unroll
  for (int i = 0; i < 4; ++i) {
    float4 o;
    o.x = acc[i][0] + bb[0]; o.y = acc[i][1] + bb[1];
    o.z = acc[i][2] + bb[2]; o.w = acc[i][3] + bb[3];
    *(float4*)(C + (size_t)(row0 + i) * ldc + col0) = o;
  }
}

// Column stats over rows: X layout [B][R][rowStride], channels = first 256 of row.
// grid = (B, R/rowsPerBlock), block = 256 (thread == channel). Atomic partial sums.
__global__ __launch_bounds__(256) void stats_kernel(const float* __restrict__ X,
    long batchStride, int rowStride, int rowsPerBlock,
    float* __restrict__ sum, float* __restrict__ sumsq)
{
  const int b = blockIdx.x, c = threadIdx.x;
  const long r0 = (long)blockIdx.y * rowsPerBlock;
  const float* base = X + (long)b * batchStride + r0 * rowStride + c;
  float s = 0.f, ss = 0.f;
  for (int r = 0; r < rowsPerBlock; ++r) {
    float v = base[(long)r * rowStride];
    s += v; ss += v * v;
  }
  atomicAdd(&sum[b * 256 + c], s);
  atomicAdd(&sumsq[b * 256 + c], ss);
}

__global__ __launch_bounds__(256) void finalize_stats(const float* __restrict__ sum,
    const float* __restrict__ sumsq, float invR,
    float* __restrict__ mean, float* __restrict__ rstd)
{
  int i = blockIdx.x * 256 + threadIdx.x;   // B*256 = 1024 entries
  float m = sum[i] * invR;
  float v = sumsq[i] * invR - m * m;
  mean[i] = m;
  rstd[i] = rsqrtf(v + 1e-5f);
}

// Normalize k channels (cols 0..255 of kv rows) in place. grid (B, HW/16), block 256.
__global__ __launch_bounds__(256) void knorm_kernel(float* __restrict__ kv,
    const float* __restrict__ mean, const float* __restrict__ rstd)
{
  const int b = blockIdx.x, c = threadIdx.x;
  const int n1 = blockIdx.y * 16;
  const float m = mean[b * 256 + c], r = rstd[b * 256 + c];
  for (int i = 0; i < 16; ++i) {
    size_t idx = ((size_t)(b * HWn + n1 + i)) * 512 + c;
    kv[idx] = (kv[idx] - m) * r;
  }
}

// Flash attention. q: [B][NL][256] f32, kv: [B][HW][512] f32 (k normalized, v at +256).
// out: [B][NL][256] f32. grid = (B*NH, NL/64), block = 256.
__global__ __launch_bounds__(256) void attn_kernel(const float* __restrict__ q,
    const float* __restrict__ kv, float* __restrict__ out)
{
  const int bh = blockIdx.x, b = bh >> 3, h = bh & 7;
  const int l0 = blockIdx.y * 64;
  const int tid = threadIdx.x;
  const int ty = tid >> 4, tx = tid & 15;

  __shared__ float qs[32][68];  // [d][l]
  __shared__ float ks[32][68];  // [d][n]
  __shared__ float vs[64][36];  // [n][dv]
  __shared__ float ps[64][68];  // [n][l]  (softmax probs)

  // stage q tile (64 l-rows x 32 channels), transposed into qs[d][l]
#pragma unroll
  for (int it = 0; it < 2; ++it) {
    int c = tid + it * 256;
    int l = c >> 3, dq = (c & 7) << 2;
    float v[4];
    load4f(q + ((size_t)(b * NL + l0 + l)) * 256 + h * 32 + dq, v);
    qs[dq + 0][l] = v[0]; qs[dq + 1][l] = v[1]; qs[dq + 2][l] = v[2]; qs[dq + 3][l] = v[3];
  }

  float mrow[4], drow[4], acc[4][2];
#pragma unroll
  for (int i = 0; i < 4; ++i) { mrow[i] = -1e30f; drow[i] = 0.f; acc[i][0] = 0.f; acc[i][1] = 0.f; }

  for (int n0 = 0; n0 < HWn; n0 += 64) {
    __syncthreads();  // protect ks/vs/ps from previous iteration's readers
#pragma unroll
    for (int it = 0; it < 2; ++it) {
      int c = tid + it * 256;
      int n = c >> 3, dq = (c & 7) << 2;
      const size_t rb = ((size_t)(b * HWn + n0 + n)) * 512 + h * 32 + dq;
      float kvv[4], vv[4];
      load4f(kv + rb, kvv);
      ks[dq + 0][n] = kvv[0]; ks[dq + 1][n] = kvv[1]; ks[dq + 2][n] = kvv[2]; ks[dq + 3][n] = kvv[3];
      load4f(kv + rb + 256, vv);
      *(float4*)&vs[n][dq] = *(const float4*)vv;
    }
    __syncthreads();

    // scores s[l=4ty+i][n=4tx+j]
    float s[4][4] = {};
#pragma unroll
    for (int d = 0; d < 32; ++d) {
      float a[4], kk[4];
      *(float4*)a  = *(const float4*)&qs[d][ty << 2];
      *(float4*)kk = *(const float4*)&ks[d][tx << 2];
#pragma unroll
      for (int i = 0; i < 4; ++i)
#pragma unroll
        for (int j = 0; j < 4; ++j)
          s[i][j] = fmaf(a[i], kk[j], s[i][j]);
    }

    // online softmax per row; row l = 4ty+i lives in the 16 lanes sharing ty
#pragma unroll
    for (int i = 0; i < 4; ++i) {
#pragma unroll
      for (int j = 0; j < 4; ++j) s[i][j] *= 0.0625f;
      float rmax = fmaxf(fmaxf(s[i][0], s[i][1]), fmaxf(s[i][2], s[i][3]));
      rmax = fmaxf(rmax, __shfl_xor(rmax, 1, 16));
      rmax = fmaxf(rmax, __shfl_xor(rmax, 2, 16));
      rmax = fmaxf(rmax, __shfl_xor(rmax, 4, 16));
      rmax = fmaxf(rmax, __shfl_xor(rmax, 8, 16));
      float mnew  = fmaxf(mrow[i], rmax);
      float alpha = __expf(mrow[i] - mnew);
      float p[4], rsum = 0.f;
#pragma unroll
      for (int j = 0; j < 4; ++j) { p[j] = __expf(s[i][j] - mnew); rsum += p[j]; }
      rsum += __shfl_xor(rsum, 1, 16);
      rsum += __shfl_xor(rsum, 2, 16);
      rsum += __shfl_xor(rsum, 4, 16);
      rsum += __shfl_xor(rsum, 8, 16);
      drow[i] = drow[i] * alpha + rsum;
      mrow[i] = mnew;
      acc[i][0] *= alpha; acc[i][1] *= alpha;
#pragma unroll
      for (int j = 0; j < 4; ++j) ps[(tx << 2) + j][(ty << 2) + i] = p[j];
    }
    __syncthreads();

    // PV: thread owns rows l=4ty+i, cols dv = 2tx, 2tx+1
#pragma unroll 4
    for (int n = 0; n < 64; ++n) {
      float p[4];
      *(float4*)p = *(const float4*)&ps[n][ty << 2];
      float v0 = vs[n][tx << 1], v1 = vs[n][(tx << 1) + 1];
#pragma unroll
      for (int i = 0; i < 4; ++i) {
        acc[i][0] = fmaf(p[i], v0, acc[i][0]);
        acc[i][1] = fmaf(p[i], v1, acc[i][1]);
      }
    }
  }

#pragma unroll
  for (int i = 0; i < 4; ++i) {
    float inv = 1.0f / drow[i];
    size_t o = ((size_t)(b * NL + l0 + (ty << 2) + i)) * 256 + h * 32 + (tx << 1);
    out[o]     = acc[i][0] * inv;
    out[o + 1] = acc[i][1] * inv;
  }
}

// out[b][l][o] = (proj[b][l][o] - mean[b][o]) * rstd[b][o]  (f32 out)
// grid (B, NL/16), block 256 (thread == o)
__global__ __launch_bounds__(256) void final_out(const float* __restrict__ proj,
    const float* __restrict__ mean, const float* __restrict__ rstd,
    float* __restrict__ out)
{
  const int b = blockIdx.x, o = threadIdx.x;
  const int l1 = blockIdx.y * 16;
  const float m = mean[b * 256 + o], r = rstd[b * 256 + o];
  for (int i = 0; i < 16; ++i) {
    size_t idx = ((size_t)(b * NL + l1 + i)) * 256 + o;
    out[idx] = (proj[idx] - m) * r;
  }
}

extern "C" void kernel_launch(void* const* d_in, const int* in_sizes, int n_in,
                              void* d_out, int out_size, void* d_ws, size_t ws_size,
                              hipStream_t stream)
{
  const float* l  = (const float*)d_in[0];
  const float* x  = (const float*)d_in[1];
  const float* Wq = (const float*)d_in[2];
  const float* bq = (const float*)d_in[3];
  const float* Wk = (const float*)d_in[4];
  const float* bk = (const float*)d_in[5];
  const float* Wv = (const float*)d_in[6];
  const float* bv = (const float*)d_in[7];
  const float* Ww = (const float*)d_in[8];
  const float* bw = (const float*)d_in[9];
  float* out = (float*)d_out;

  float* wsf   = (float*)d_ws;
  float* q_ws  = wsf;                                   // [B][NL][256]
  float* kv_ws = q_ws  + (size_t)Bn * NL * CK;          // [B][HW][512] (k | v)
  float* ao_ws = kv_ws + (size_t)Bn * HWn * 512;        // [B][NL][256]
  float* pj_ws = ao_ws + (size_t)Bn * NL * CK;          // [B][NL][256] (pre-norm proj)
  float* st    = pj_ws + (size_t)Bn * NL * CK;
  float* ksum  = st;             float* ksq   = st + 1024;
  float* psum  = st + 2048;      float* psq   = st + 3072;
  float* kmean = st + 4096;      float* krstd = st + 5120;
  float* pmean = st + 6144;      float* prstd = st + 7168;

  hipMemsetAsync(st, 0, 4096 * sizeof(float), stream);

  dim3 blk(256);
  // q = l @ Wq^T + bq              [4096 x 256], K=512
  gemm_nt<<<dim3(64, 4), blk, 0, stream>>>(l, 512, Wq, 512, bq, q_ws, 256, 512);
  // k = x @ Wk^T + bk              [16384 x 256] into kv cols 0..255
  gemm_nt<<<dim3(256, 4), blk, 0, stream>>>(x, 512, Wk, 512, bk, kv_ws, 512, 512);
  // v = x @ Wv^T + bv              into kv cols 256..511
  gemm_nt<<<dim3(256, 4), blk, 0, stream>>>(x, 512, Wv, 512, bv, kv_ws + 256, 512, 512);
  // instance-norm stats of k over HW
  stats_kernel<<<dim3(4, 8), blk, 0, stream>>>(kv_ws, (long)HWn * 512, 512, 512, ksum, ksq);
  finalize_stats<<<4, 256, 0, stream>>>(ksum, ksq, 1.0f / HWn, kmean, krstd);
  knorm_kernel<<<dim3(4, 256), blk, 0, stream>>>(kv_ws, kmean, krstd);
  // flash attention
  attn_kernel<<<dim3(Bn * NH, NL / 64), blk, 0, stream>>>(q_ws, kv_ws, ao_ws);
  // proj = attn_out @ Ww^T + bw    [4096 x 256], K=256
  gemm_nt<<<dim3(64, 4), blk, 0, stream>>>(ao_ws, 256, Ww, 256, bw, pj_ws, 256, 256);
  // instance-norm stats of proj over NL
  stats_kernel<<<dim3(4, 4), blk, 0, stream>>>(pj_ws, (long)NL * 256, 256, 256, psum, psq);
  finalize_stats<<<4, 256, 0, stream>>>(psum, psq, 1.0f / NL, pmean, prstd);
  final_out<<<dim3(4, 64), blk, 0, stream>>>(pj_ws, pmean, prstd, out);
}

// Round 3
// 556.390 us; speedup vs baseline: 1.4327x; 1.4327x over previous
//
#include <hip/hip_runtime.h>

constexpr int Bn   = 4;
constexpr int NL   = 1024;
constexpr int HWn  = 4096;
constexpr int NH   = 8;
// dk = dv = 32, scale = Ck^-0.5 = 0.0625

typedef __attribute__((ext_vector_type(8))) short bf16x8;
typedef __attribute__((ext_vector_type(4))) float f32x4;
#define MFMA16 __builtin_amdgcn_mfma_f32_16x16x32_bf16

__device__ __forceinline__ float b2f(unsigned short u) {
  union { unsigned int i; float f; } x; x.i = ((unsigned int)u) << 16; return x.f;
}
__device__ __forceinline__ unsigned short f2b(float f) {
  union { float f; unsigned int i; } x; x.f = f;
  unsigned int r = x.i + 0x7fffu + ((x.i >> 16) & 1u);   // RNE
  return (unsigned short)(r >> 16);
}
__device__ __forceinline__ void load4f(const float* p, float* o) {
  float4 v = *(const float4*)p; o[0] = v.x; o[1] = v.y; o[2] = v.z; o[3] = v.w;
}

// ---------- f32 -> bf16 conversion (n % 4 == 0) ----------
__global__ __launch_bounds__(256) void conv_bf16(const float* __restrict__ src,
    unsigned short* __restrict__ dst, int n)
{
  int i = (blockIdx.x * 256 + threadIdx.x) * 4;
  if (i < n) {
    float4 v = *(const float4*)(src + i);
    ushort4 o; o.x = f2b(v.x); o.y = f2b(v.y); o.z = f2b(v.z); o.w = f2b(v.w);
    *(ushort4*)(dst + i) = o;
  }
}

// ---------- bf16 MFMA GEMM: C[m,n] = sum_k A[m,k]*W[n,k] + bias[n], N=256 fixed ----------
// A: bf16 [M x K], W: bf16 [256 x K], out: bf16 [M x 256]. grid = M/64, block 256.
__global__ __launch_bounds__(256) void gemm16(const unsigned short* __restrict__ A,
    const unsigned short* __restrict__ W, const float* __restrict__ bias,
    unsigned short* __restrict__ out, int K)
{
  const int w = threadIdx.x >> 6, lane = threadIdx.x & 63;
  const int quad = lane >> 4, l15 = lane & 15;
  const int m0 = blockIdx.x * 64 + w * 16;
  f32x4 acc[16];
#pragma unroll
  for (int t = 0; t < 16; ++t) acc[t] = (f32x4){0.f, 0.f, 0.f, 0.f};
  const unsigned short* Arow = A + (size_t)(m0 + l15) * K + quad * 8;
  for (int k0 = 0; k0 < K; k0 += 32) {
    bf16x8 af = *(const bf16x8*)(Arow + k0);
#pragma unroll
    for (int t = 0; t < 16; ++t) {
      bf16x8 wf = *(const bf16x8*)(W + (size_t)(t * 16 + l15) * K + k0 + quad * 8);
      acc[t] = MFMA16(af, wf, acc[t], 0, 0, 0);
    }
  }
  // C/D layout: row = m0 + quad*4 + r, col = l15 + 16t
#pragma unroll
  for (int t = 0; t < 16; ++t) {
    int col = l15 + 16 * t; float bb = bias[col];
#pragma unroll
    for (int r = 0; r < 4; ++r)
      out[(size_t)(m0 + quad * 4 + r) * 256 + col] = f2b(acc[t][r] + bb);
  }
}

// ---------- column stats (bf16 input), thread == channel ----------
__global__ __launch_bounds__(256) void stats_bf16(const unsigned short* __restrict__ X,
    long batchStride, int rowsPerBlock,
    float* __restrict__ sum, float* __restrict__ sumsq)
{
  const int b = blockIdx.x, c = threadIdx.x;
  const long r0 = (long)blockIdx.y * rowsPerBlock;
  const unsigned short* base = X + (long)b * batchStride + r0 * 256 + c;
  float s = 0.f, ss = 0.f;
  for (int r = 0; r < rowsPerBlock; ++r) {
    float v = b2f(base[(long)r * 256]);
    s += v; ss += v * v;
  }
  atomicAdd(&sum[b * 256 + c], s);
  atomicAdd(&sumsq[b * 256 + c], ss);
}

// ---------- column stats (f32 input) for proj ----------
__global__ __launch_bounds__(256) void stats_kernel(const float* __restrict__ X,
    long batchStride, int rowsPerBlock,
    float* __restrict__ sum, float* __restrict__ sumsq)
{
  const int b = blockIdx.x, c = threadIdx.x;
  const long r0 = (long)blockIdx.y * rowsPerBlock;
  const float* base = X + (long)b * batchStride + r0 * 256 + c;
  float s = 0.f, ss = 0.f;
  for (int r = 0; r < rowsPerBlock; ++r) {
    float v = base[(long)r * 256];
    s += v; ss += v * v;
  }
  atomicAdd(&sum[b * 256 + c], s);
  atomicAdd(&sumsq[b * 256 + c], ss);
}

__global__ __launch_bounds__(256) void finalize_stats(const float* __restrict__ sum,
    const float* __restrict__ sumsq, float invR,
    float* __restrict__ mean, float* __restrict__ rstd)
{
  int i = blockIdx.x * 256 + threadIdx.x;
  float m = sum[i] * invR;
  float v = sumsq[i] * invR - m * m;
  mean[i] = m;
  rstd[i] = rsqrtf(v + 1e-5f);
}

// ---------- k instance-norm: kpre(bf16) -> kbuf(bf16). grid (B, HW/16) ----------
__global__ __launch_bounds__(256) void knorm_bf16(const unsigned short* __restrict__ kpre,
    unsigned short* __restrict__ kbuf,
    const float* __restrict__ mean, const float* __restrict__ rstd)
{
  const int b = blockIdx.x, c = threadIdx.x;
  const int n1 = blockIdx.y * 16;
  const float m = mean[b * 256 + c], r = rstd[b * 256 + c];
  for (int i = 0; i < 16; ++i) {
    size_t idx = ((size_t)(b * HWn + n1 + i)) * 256 + c;
    kbuf[idx] = f2b((b2f(kpre[idx]) - m) * r);
  }
}

// ---------- V transpose: vbuf[b][n][c] -> vT[b][h][dv][n]. grid (B, HW/64) ----------
__global__ __launch_bounds__(256) void vtrans(const unsigned short* __restrict__ vbuf,
    unsigned short* __restrict__ vT)
{
  __shared__ unsigned short ts[64][264];   // [n][c], pad 8 -> phase2 conflict-free
  const int b = blockIdx.x, n0 = blockIdx.y * 64;
  const int c = threadIdx.x;
  for (int r = 0; r < 64; ++r)
    ts[r][c] = vbuf[((size_t)(b * HWn + n0 + r)) * 256 + c];
  __syncthreads();
  unsigned short tmp[64];
  for (int r = 0; r < 64; ++r) tmp[r] = ts[r][c];
  unsigned short* dst = vT + ((size_t)((b * NH + (c >> 5)) * 32 + (c & 31))) * HWn + n0;
#pragma unroll
  for (int i = 0; i < 8; ++i)
    *(bf16x8*)(dst + i * 8) = *(const bf16x8*)&tmp[i * 8];
}

// ---------- per-chunk V column sums: vcs[b][chunk][c] = sum_{n in 64-chunk} v ----------
__global__ __launch_bounds__(256) void vchunksum(const unsigned short* __restrict__ vbuf,
    float* __restrict__ vcs)
{
  const int b = blockIdx.x, ch = blockIdx.y, c = threadIdx.x;
  const unsigned short* p = vbuf + ((size_t)(b * HWn + ch * 64)) * 256 + c;
  float s = 0.f;
  for (int r = 0; r < 64; ++r) s += b2f(p[(size_t)r * 256]);
  vcs[(size_t)(b * 64 + ch) * 256 + c] = s;
}

// ---------- MFMA flash attention, n-split into 2 halves, zero barriers ----------
// grid (B*NH, NL/64, 2), block 256 (4 waves; wave = 16 l-rows)
__global__ __launch_bounds__(256) void attn_mfma(const unsigned short* __restrict__ qbuf,
    const unsigned short* __restrict__ kbuf, const unsigned short* __restrict__ vT,
    const float* __restrict__ vcs,
    float* __restrict__ po, float* __restrict__ pm, float* __restrict__ pd)
{
  const int bh = blockIdx.x, b = bh >> 3, h = bh & 7;
  const int l0 = blockIdx.y * 64;
  const int half = blockIdx.z;
  const int w = threadIdx.x >> 6, lane = threadIdx.x & 63;
  const int quad = lane >> 4, l15 = lane & 15;
  const size_t POsz = (size_t)Bn * NH * NL * 32, PMsz = (size_t)Bn * NH * NL;

  __shared__ unsigned short ps[4][16][72];   // wave-private P tiles (A-layout source)

  // Q A-frag, held in registers for the whole kernel: A[m=l15][k=quad*8+j]
  bf16x8 qa = *(const bf16x8*)(qbuf + ((size_t)(b * NL + l0 + w * 16 + l15)) * 256 + h * 32 + quad * 8);

  float mrow[4], drow[4];
  f32x4 oacc[2];
#pragma unroll
  for (int r = 0; r < 4; ++r) { mrow[r] = -1e30f; drow[r] = 0.f; }
  oacc[0] = (f32x4){0.f,0.f,0.f,0.f}; oacc[1] = (f32x4){0.f,0.f,0.f,0.f};

  const int cbeg = half * (HWn / 2), cend = cbeg + (HWn / 2);
  for (int c0 = cbeg; c0 < cend; c0 += 64) {
    // --- K B-frags direct from global: B[n=l15][k=quad*8+j] = kbuf[n][d] contiguous
    const unsigned short* kbase = kbuf + ((size_t)(b * HWn + c0)) * 256 + h * 32 + quad * 8;
    f32x4 z = (f32x4){0.f,0.f,0.f,0.f};
    f32x4 s[4];
#pragma unroll
    for (int t = 0; t < 4; ++t) {
      bf16x8 kb = *(const bf16x8*)(kbase + (size_t)(t * 16 + l15) * 256);
      s[t] = MFMA16(qa, kb, z, 0, 0, 0);
    }
    // --- online softmax; lane owns rows quad*4+r, cols l15+16t
    float p[4][4], crow[4], rs[4];
#pragma unroll
    for (int r = 0; r < 4; ++r) {
      float sc[4];
#pragma unroll
      for (int t = 0; t < 4; ++t) sc[t] = s[t][r] * 0.0625f;
      float rmax = fmaxf(fmaxf(sc[0], sc[1]), fmaxf(sc[2], sc[3]));
      rmax = fmaxf(rmax, __shfl_xor(rmax, 1, 16));
      rmax = fmaxf(rmax, __shfl_xor(rmax, 2, 16));
      rmax = fmaxf(rmax, __shfl_xor(rmax, 4, 16));
      rmax = fmaxf(rmax, __shfl_xor(rmax, 8, 16));
      float mnew = fmaxf(mrow[r], rmax);
      float alpha = __expf(mrow[r] - mnew);
      float rsum = 0.f;
#pragma unroll
      for (int t = 0; t < 4; ++t) { p[t][r] = __expf(sc[t] - mnew); rsum += p[t][r]; }
      rsum += __shfl_xor(rsum, 1, 16);
      rsum += __shfl_xor(rsum, 2, 16);
      rsum += __shfl_xor(rsum, 4, 16);
      rsum += __shfl_xor(rsum, 8, 16);
      crow[r] = rsum * (1.0f / 64.0f);          // chunk-mean of the row
      drow[r] = drow[r] * alpha + rsum;
      mrow[r] = mnew;
      oacc[0][r] *= alpha; oacc[1][r] *= alpha;
      rs[r] = rsum; (void)rs;
    }
    // --- centered P -> LDS (bf16), wave-private
#pragma unroll
    for (int t = 0; t < 4; ++t)
#pragma unroll
      for (int r = 0; r < 4; ++r)
        ps[w][quad * 4 + r][t * 16 + l15] = f2b(p[t][r] - crow[r]);
    asm volatile("s_waitcnt lgkmcnt(0)" ::: "memory");
    // --- PV: A[m=l15][k=n] from LDS, B[k=n][dv=l15+16*dvt] from vT (contiguous)
    const unsigned short* vbase = vT + ((size_t)bh * 32) * HWn + c0;
#pragma unroll
    for (int kh = 0; kh < 2; ++kh) {
      bf16x8 pa = *(const bf16x8*)&ps[w][l15][kh * 32 + quad * 8];
#pragma unroll
      for (int dvt = 0; dvt < 2; ++dvt) {
        bf16x8 vb = *(const bf16x8*)(vbase + (size_t)(dvt * 16 + l15) * HWn + kh * 32 + quad * 8);
        oacc[dvt] = MFMA16(pa, vb, oacc[dvt], 0, 0, 0);
      }
    }
    // --- centering correction: + crow * (chunk column-sum of V)
    const float* vc = vcs + (size_t)(b * 64 + (c0 >> 6)) * 256 + h * 32;
    float cs0 = vc[l15], cs1 = vc[l15 + 16];
#pragma unroll
    for (int r = 0; r < 4; ++r) {
      oacc[0][r] = fmaf(crow[r], cs0, oacc[0][r]);
      oacc[1][r] = fmaf(crow[r], cs1, oacc[1][r]);
    }
  }

  // --- write partials (C-layout rows quad*4+r, cols l15 / l15+16)
  const int lrow = l0 + w * 16 + quad * 4;
  float* poh = po + half * POsz;
#pragma unroll
  for (int r = 0; r < 4; ++r) {
    size_t base = ((size_t)bh * NL + lrow + r) * 32;
    poh[base + l15]      = oacc[0][r];
    poh[base + l15 + 16] = oacc[1][r];
  }
  if (l15 == 0) {
#pragma unroll
    for (int r = 0; r < 4; ++r) {
      pm[half * PMsz + (size_t)bh * NL + lrow + r] = mrow[r];
      pd[half * PMsz + (size_t)bh * NL + lrow + r] = drow[r];
    }
  }
}

// ---------- combine 2 halves -> ao[b][l][h*32+dv] (f32). grid 4096 x 256 ----------
__global__ __launch_bounds__(256) void attn_combine(const float* __restrict__ po,
    const float* __restrict__ pm, const float* __restrict__ pd, float* __restrict__ ao)
{
  const size_t POsz = (size_t)Bn * NH * NL * 32, PMsz = (size_t)Bn * NH * NL;
  int gid = blockIdx.x * 256 + threadIdx.x;       // B*H*NL*32 = 2^20
  int dv = gid & 31, l = (gid >> 5) & (NL - 1), h = (gid >> 15) & 7, b = gid >> 18;
  size_t ridx = ((size_t)(b * NH + h)) * NL + l;
  float m0 = pm[ridx], m1 = pm[PMsz + ridx];
  float d0 = pd[ridx], d1 = pd[PMsz + ridx];
  float m = fmaxf(m0, m1);
  float e0 = __expf(m0 - m), e1 = __expf(m1 - m);
  float d = d0 * e0 + d1 * e1;
  float o = (po[ridx * 32 + dv] * e0 + po[POsz + ridx * 32 + dv] * e1) / d;
  ao[((size_t)(b * NL) + l) * 256 + h * 32 + dv] = o;
}

// ---------- f32 NT gemm (kept for proj, precision-critical) ----------
__global__ __launch_bounds__(256) void gemm_nt(const float* __restrict__ A, int lda,
    const float* __restrict__ W, int ldw, const float* __restrict__ bias,
    float* __restrict__ C, int ldc, int K)
{
  __shared__ float As[32][68];
  __shared__ float Ws[32][68];
  const int bm = blockIdx.x * 64, bn = blockIdx.y * 64;
  const int tid = threadIdx.x;
  const int ty = tid >> 4, tx = tid & 15;
  float acc[4][4] = {};
  for (int k0 = 0; k0 < K; k0 += 32) {
#pragma unroll
    for (int it = 0; it < 2; ++it) {
      int c = tid + it * 256;
      int m = c >> 3, kq = (c & 7) << 2;
      float av[4], wv[4];
      load4f(A + (size_t)(bm + m) * lda + k0 + kq, av);
      load4f(W + (size_t)(bn + m) * ldw + k0 + kq, wv);
      As[kq + 0][m] = av[0]; As[kq + 1][m] = av[1]; As[kq + 2][m] = av[2]; As[kq + 3][m] = av[3];
      Ws[kq + 0][m] = wv[0]; Ws[kq + 1][m] = wv[1]; Ws[kq + 2][m] = wv[2]; Ws[kq + 3][m] = wv[3];
    }
    __syncthreads();
#pragma unroll
    for (int kk = 0; kk < 32; ++kk) {
      float a[4], w[4];
      *(float4*)a = *(const float4*)&As[kk][ty << 2];
      *(float4*)w = *(const float4*)&Ws[kk][tx << 2];
#pragma unroll
      for (int i = 0; i < 4; ++i)
#pragma unroll
        for (int j = 0; j < 4; ++j)
          acc[i][j] = fmaf(a[i], w[j], acc[i][j]);
    }
    __syncthreads();
  }
  const int row0 = bm + (ty << 2), col0 = bn + (tx << 2);
  float bb[4];
#pragma unroll
  for (int j = 0; j < 4; ++j) bb[j] = bias[col0 + j];
#pragma unroll
  for (int i = 0; i < 4; ++i) {
    float4 o;
    o.x = acc[i][0] + bb[0]; o.y = acc[i][1] + bb[1];
    o.z = acc[i][2] + bb[2]; o.w = acc[i][3] + bb[3];
    *(float4*)(C + (size_t)(row0 + i) * ldc + col0) = o;
  }
}

// ---------- final norm ----------
__global__ __launch_bounds__(256) void final_out(const float* __restrict__ proj,
    const float* __restrict__ mean, const float* __restrict__ rstd,
    float* __restrict__ out)
{
  const int b = blockIdx.x, o = threadIdx.x;
  const int l1 = blockIdx.y * 16;
  const float m = mean[b * 256 + o], r = rstd[b * 256 + o];
  for (int i = 0; i < 16; ++i) {
    size_t idx = ((size_t)(b * NL + l1 + i)) * 256 + o;
    out[idx] = (proj[idx] - m) * r;
  }
}

extern "C" void kernel_launch(void* const* d_in, const int* in_sizes, int n_in,
                              void* d_out, int out_size, void* d_ws, size_t ws_size,
                              hipStream_t stream)
{
  const float* l  = (const float*)d_in[0];
  const float* x  = (const float*)d_in[1];
  const float* Wq = (const float*)d_in[2];
  const float* bq = (const float*)d_in[3];
  const float* Wk = (const float*)d_in[4];
  const float* bk = (const float*)d_in[5];
  const float* Wv = (const float*)d_in[6];
  const float* bv = (const float*)d_in[7];
  const float* Ww = (const float*)d_in[8];
  const float* bw = (const float*)d_in[9];
  float* out = (float*)d_out;

  // ushort pool
  unsigned short* up = (unsigned short*)d_ws;
  unsigned short* l_bf  = up;                         // 4*1024*512
  unsigned short* x_bf  = l_bf  + 2097152;            // 4*4096*512
  unsigned short* wq_bf = x_bf  + 8388608;            // 256*512
  unsigned short* wk_bf = wq_bf + 131072;
  unsigned short* wv_bf = wk_bf + 131072;
  unsigned short* qbuf  = wv_bf + 131072;             // 4*1024*256
  unsigned short* kpre  = qbuf  + 1048576;            // 4*4096*256
  unsigned short* kbuf  = kpre  + 4194304;
  unsigned short* vbuf  = kbuf  + 4194304;
  unsigned short* vT    = vbuf  + 4194304;
  // float pool (57,409,536 bytes consumed above)
  float* fp   = (float*)((char*)d_ws + 57409536);
  float* vcs  = fp;                                   // 4*64*256
  float* po   = vcs + 65536;                          // 2*4*8*1024*32
  float* pm   = po  + 2097152;                        // 2*32768
  float* pd   = pm  + 65536;
  float* ao   = pd  + 65536;                          // 4*1024*256
  float* pj   = ao  + 1048576;
  float* st   = pj  + 1048576;                        // stats scratch
  float* ksum = st;           float* ksq   = st + 1024;
  float* psum = st + 2048;    float* psq   = st + 3072;
  float* kmean= st + 4096;    float* krstd = st + 5120;
  float* pmean= st + 6144;    float* prstd = st + 7168;

  hipMemsetAsync(st, 0, 4096 * sizeof(float), stream);

  dim3 blk(256);
  // bf16 conversions
  conv_bf16<<<2048, blk, 0, stream>>>(l,  l_bf,  2097152);
  conv_bf16<<<8192, blk, 0, stream>>>(x,  x_bf,  8388608);
  conv_bf16<<<128,  blk, 0, stream>>>(Wq, wq_bf, 131072);
  conv_bf16<<<128,  blk, 0, stream>>>(Wk, wk_bf, 131072);
  conv_bf16<<<128,  blk, 0, stream>>>(Wv, wv_bf, 131072);
  // MFMA gemms: q, k(pre-norm), v
  gemm16<<<64,  blk, 0, stream>>>(l_bf, wq_bf, bq, qbuf, 512);
  gemm16<<<256, blk, 0, stream>>>(x_bf, wk_bf, bk, kpre, 512);
  gemm16<<<256, blk, 0, stream>>>(x_bf, wv_bf, bv, vbuf, 512);
  // k instance-norm
  stats_bf16<<<dim3(4, 8), blk, 0, stream>>>(kpre, (long)HWn * 256, 512, ksum, ksq);
  finalize_stats<<<4, 256, 0, stream>>>(ksum, ksq, 1.0f / HWn, kmean, krstd);
  knorm_bf16<<<dim3(4, 256), blk, 0, stream>>>(kpre, kbuf, kmean, krstd);
  // V transpose + chunk sums
  vtrans<<<dim3(4, 64), blk, 0, stream>>>(vbuf, vT);
  vchunksum<<<dim3(4, 64), blk, 0, stream>>>(vbuf, vcs);
  // flash attention (2 n-halves) + combine
  attn_mfma<<<dim3(Bn * NH, NL / 64, 2), blk, 0, stream>>>(qbuf, kbuf, vT, vcs, po, pm, pd);
  attn_combine<<<4096, blk, 0, stream>>>(po, pm, pd, ao);
  // proj (f32 for precision) + final norm
  gemm_nt<<<dim3(64, 4), blk, 0, stream>>>(ao, 256, Ww, 256, bw, pj, 256, 256);
  stats_kernel<<<dim3(4, 4), blk, 0, stream>>>(pj, (long)NL * 256, 256, psum, psq);
  finalize_stats<<<4, 256, 0, stream>>>(psum, psq, 1.0f / NL, pmean, prstd);
  final_out<<<dim3(4, 64), blk, 0, stream>>>(pj, pmean, prstd, out);
}

// Round 4
// 355.746 us; speedup vs baseline: 2.2407x; 1.5640x over previous
//
#include <hip/hip_runtime.h>

constexpr int Bn = 4, NL = 1024, HWn = 4096, NH = 8;

typedef __attribute__((ext_vector_type(8))) short bf16x8;
typedef __attribute__((ext_vector_type(4))) float f32x4;
#define MFMA16 __builtin_amdgcn_mfma_f32_16x16x32_bf16

__device__ __forceinline__ float b2f(unsigned short u) {
  union { unsigned int i; float f; } x; x.i = ((unsigned int)u) << 16; return x.f;
}
__device__ __forceinline__ unsigned short f2b(float f) {
  union { float f; unsigned int i; } x; x.f = f;
  unsigned int r = x.i + 0x7fffu + ((x.i >> 16) & 1u);   // RNE
  return (unsigned short)(r >> 16);
}
__device__ __forceinline__ void load4f(const float* p, float* o) {
  float4 v = *(const float4*)p; o[0] = v.x; o[1] = v.y; o[2] = v.z; o[3] = v.w;
}

// ---------- f32 -> bf16 ----------
__global__ __launch_bounds__(256) void conv_bf16(const float* __restrict__ src,
    unsigned short* __restrict__ dst, int n)
{
  int i = (blockIdx.x * 256 + threadIdx.x) * 4;
  if (i < n) {
    float4 v = *(const float4*)(src + i);
    ushort4 o; o.x = f2b(v.x); o.y = f2b(v.y); o.z = f2b(v.z); o.w = f2b(v.w);
    *(ushort4*)(dst + i) = o;
  }
}

// ---------- pack W [256x512] f32 -> frag-major bf16 ----------
// piece idx: ((k0t*16 + t)*64 + lane)*8 + j  = W[t*16+(lane&15)][k0t*32+(lane>>4)*8+j]
__global__ __launch_bounds__(256) void pack_w(const float* __restrict__ W0,
    const float* __restrict__ W1, const float* __restrict__ W2,
    unsigned short* __restrict__ P0, unsigned short* __restrict__ P1,
    unsigned short* __restrict__ P2)
{
  const float* src = blockIdx.y == 0 ? W0 : blockIdx.y == 1 ? W1 : W2;
  unsigned short* dst = blockIdx.y == 0 ? P0 : blockIdx.y == 1 ? P1 : P2;
  int idx = blockIdx.x * 256 + threadIdx.x;        // 0..16383
  int lane = idx & 63, tc = idx >> 6;
  int t = tc & 15, k0t = tc >> 4;
  const float* s = src + (size_t)(t * 16 + (lane & 15)) * 512 + k0t * 32 + (lane >> 4) * 8;
  unsigned short o[8];
#pragma unroll
  for (int j = 0; j < 8; ++j) o[j] = f2b(s[j]);
  *(bf16x8*)(dst + (size_t)idx * 8) = *(const bf16x8*)o;
}

// ---------- fused q/k/v GEMM ----------
// blocks 0..511: K+V over x (m0=id*32); 512..639: Q over l.
// outputs: kh/vh head-major [b][h][n][32] bf16, qbuf row-major [b*NL][256] bf16
__global__ __launch_bounds__(256) void gemm_qkv(
    const unsigned short* __restrict__ xbf, const unsigned short* __restrict__ lbf,
    const unsigned short* __restrict__ wkp, const unsigned short* __restrict__ wvp,
    const unsigned short* __restrict__ wqp,
    const float* __restrict__ bk, const float* __restrict__ bv, const float* __restrict__ bq,
    unsigned short* __restrict__ kh, unsigned short* __restrict__ vh,
    unsigned short* __restrict__ qbuf)
{
  __shared__ unsigned short ct[2][32][264];
  const int id = blockIdx.x;
  const int tid = threadIdx.x, w = tid >> 6, lane = tid & 63;
  const int quad = lane >> 4, l15 = lane & 15;
  const bool isQ = id >= 512;
  const int m0 = isQ ? (id - 512) * 32 : id * 32;
  const unsigned short* A = isQ ? lbf : xbf;
  const int rows16 = m0 + (w & 1) * 16;
  const int tbase = (w >> 1) * 8;
  const unsigned short* Arow = A + (size_t)(rows16 + l15) * 512 + quad * 8;
  const unsigned short* W0 = isQ ? wqp : wkp;

  f32x4 acc[2][8];
#pragma unroll
  for (int p = 0; p < 2; ++p)
#pragma unroll
    for (int ti = 0; ti < 8; ++ti) acc[p][ti] = (f32x4){0.f, 0.f, 0.f, 0.f};

  for (int k0t = 0; k0t < 16; ++k0t) {
    bf16x8 af = *(const bf16x8*)(Arow + k0t * 32);
#pragma unroll
    for (int ti = 0; ti < 8; ++ti) {
      int t = tbase + ti;
      bf16x8 wf = *(const bf16x8*)(W0 + ((size_t)(k0t * 16 + t) * 64 + lane) * 8);
      acc[0][ti] = MFMA16(af, wf, acc[0][ti], 0, 0, 0);
      if (!isQ) {
        bf16x8 wf2 = *(const bf16x8*)(wvp + ((size_t)(k0t * 16 + t) * 64 + lane) * 8);
        acc[1][ti] = MFMA16(af, wf2, acc[1][ti], 0, 0, 0);
      }
    }
  }
  // epilogue: bias + bf16 into LDS tile(s)
  const int nparts = isQ ? 1 : 2;
  for (int p = 0; p < nparts; ++p) {
    const float* bias = isQ ? bq : (p == 0 ? bk : bv);
#pragma unroll
    for (int ti = 0; ti < 8; ++ti) {
      int col = (tbase + ti) * 16 + l15;
      float bb = bias[col];
#pragma unroll
      for (int r = 0; r < 4; ++r)
        ct[p][(w & 1) * 16 + quad * 4 + r][col] = f2b(acc[p][ti][r] + bb);
    }
  }
  __syncthreads();
  // dense writeout
  if (isQ) {
    int row = tid >> 3, ch = tid & 7;
    unsigned short* dst = qbuf + (size_t)(m0 + row) * 256 + ch * 32;
#pragma unroll
    for (int k = 0; k < 4; ++k)
      *(bf16x8*)(dst + k * 8) = *(const bf16x8*)&ct[0][row][ch * 32 + k * 8];
  } else {
    int b = m0 >> 12, n0 = m0 & 4095;
    int h = tid >> 5, row = tid & 31;
    for (int p = 0; p < 2; ++p) {
      unsigned short* dst = (p == 0 ? kh : vh) + ((size_t)(b * 8 + h) * 4096 + n0 + row) * 32;
#pragma unroll
      for (int k = 0; k < 4; ++k)
        *(bf16x8*)(dst + k * 8) = *(const bf16x8*)&ct[p][row][h * 32 + k * 8];
    }
  }
}

// ---------- k stats: rstd per (b,h,d) over all n (mean folds out of softmax) ----------
__global__ __launch_bounds__(256) void kstats(const unsigned short* __restrict__ kh,
    float* __restrict__ krstd)
{
  const int bh = blockIdx.x, t = threadIdx.x, d = t & 31, g = t >> 5;
  const unsigned short* base = kh + (size_t)bh * 4096 * 32;
  float s = 0.f, ss = 0.f;
  for (int i = 0; i < 512; ++i) {
    float v = b2f(base[(size_t)(g + i * 8) * 32 + d]);
    s += v; ss += v * v;
  }
  __shared__ float rs[256], rss[256];
  rs[t] = s; rss[t] = ss;
  __syncthreads();
  if (t < 32) {
    for (int g2 = 1; g2 < 8; ++g2) { s += rs[t + g2 * 32]; ss += rss[t + g2 * 32]; }
    float m = s * (1.f / 4096.f);
    float var = ss * (1.f / 4096.f) - m * m;
    krstd[bh * 32 + t] = rsqrtf(var + 1e-5f);
  }
}

// ---------- V quarter-column-sums: vcs[((b*4+half)*8+h)*32+d] = sum over 1024 n ----------
__global__ __launch_bounds__(256) void vsum(const unsigned short* __restrict__ vh,
    float* __restrict__ vcs)
{
  const int x = blockIdx.x;                 // 128 blocks
  const int b = x >> 5, half = (x >> 3) & 3, h = x & 7;
  const int t = threadIdx.x, d = t & 31, g = t >> 5;
  const unsigned short* base = vh + ((size_t)(b * 8 + h) * 4096 + half * 1024) * 32;
  float s = 0.f;
  for (int i = 0; i < 128; ++i) s += b2f(base[(size_t)(g + i * 8) * 32 + d]);
  __shared__ float rs[256];
  rs[t] = s;
  __syncthreads();
  if (t < 32) {
    for (int g2 = 1; g2 < 8; ++g2) s += rs[t + g2 * 32];
    vcs[((b * 4 + half) * 8 + h) * 32 + t] = s;
  }
}

// ---------- pack V head-major -> frag-major for PV B-frags ----------
// vfrag piece (chunk,kh2,dvt,lane,j) = V[n=chunk*64+kh2*32+(lane>>4)*8+j][d=dvt*16+(lane&15)]
__global__ __launch_bounds__(256) void vpack(const unsigned short* __restrict__ vh,
    unsigned short* __restrict__ vfrag)
{
  __shared__ unsigned short vt[256][42];    // pad 42: 2-way banks, dword-aligned pieces
  const int bh = blockIdx.x >> 4, slab = blockIdx.x & 15;   // 512 blocks
  const unsigned short* src = vh + ((size_t)bh * 4096 + slab * 256) * 32;
  const int t = threadIdx.x;
#pragma unroll
  for (int i = 0; i < 4; ++i) {
    int p = i * 256 + t;                    // 0..1023
    int n = p >> 2, piece = p & 3;
    uint4 v = *(const uint4*)(src + (size_t)n * 32 + piece * 8);
    unsigned int* lrow = (unsigned int*)&vt[n][piece * 8];
    lrow[0] = v.x; lrow[1] = v.y; lrow[2] = v.z; lrow[3] = v.w;
  }
  __syncthreads();
#pragma unroll
  for (int i = 0; i < 4; ++i) {
    int op = i * 256 + t;                   // 0..1023
    int lanep = op & 63, rest = op >> 6;
    int dvt = rest & 1, kh2 = (rest >> 1) & 1, chunkl = rest >> 2;   // 0..3
    int lq = lanep >> 4, ll = lanep & 15;
    unsigned short o[8];
#pragma unroll
    for (int j = 0; j < 8; ++j)
      o[j] = vt[chunkl * 64 + kh2 * 32 + lq * 8 + j][dvt * 16 + ll];
    size_t dst = ((((size_t)bh * 64 + slab * 4 + chunkl) * 2 + kh2) * 2 + dvt) * 512 + lanep * 8;
    *(bf16x8*)(vfrag + dst) = *(const bf16x8*)o;
  }
}

// ---------- MFMA flash attention: no-max exp, constant-1 centered P, 4-way n-split ----------
// grid (32, 16, 4), block 256 (4 waves, wave = 16 l-rows)
__global__ __launch_bounds__(256) void attn_mfma(const unsigned short* __restrict__ qbuf,
    const unsigned short* __restrict__ kh, const unsigned short* __restrict__ vfrag,
    const float* __restrict__ krstd, const float* __restrict__ vcs,
    float* __restrict__ po, float* __restrict__ pd)
{
  const int bh = blockIdx.x, b = bh >> 3, h = bh & 7;
  const int l0 = blockIdx.y * 64, half = blockIdx.z;
  const int w = threadIdx.x >> 6, lane = threadIdx.x & 63;
  const int quad = lane >> 4, l15 = lane & 15;
  const size_t POsz = (size_t)32 * NL * 32, PDsz = (size_t)32 * NL;

  __shared__ unsigned short ps[4][16][72];

  // q with krstd and 1/16 scale folded in (k-mean term is softmax-invariant)
  bf16x8 qa;
  {
    bf16x8 qr = *(const bf16x8*)(qbuf + ((size_t)(b * NL + l0 + w * 16 + l15)) * 256 + h * 32 + quad * 8);
    const float* rp = krstd + bh * 32 + quad * 8;
    const unsigned short* qq = (const unsigned short*)&qr;
    unsigned short tmp[8];
#pragma unroll
    for (int j = 0; j < 8; ++j) tmp[j] = f2b(b2f(qq[j]) * rp[j] * 0.0625f);
    qa = *(const bf16x8*)tmp;
  }

  float drow[4] = {0.f, 0.f, 0.f, 0.f};
  f32x4 oacc[2];
  oacc[0] = (f32x4){0.f,0.f,0.f,0.f}; oacc[1] = (f32x4){0.f,0.f,0.f,0.f};

  const unsigned short* kbase = kh + (size_t)bh * 4096 * 32;
  const unsigned short* vbase = vfrag + (size_t)bh * 64 * 2048;
  const int cbeg = half * 1024, cend = cbeg + 1024;

  for (int c0 = cbeg; c0 < cend; c0 += 64) {
    f32x4 z = (f32x4){0.f,0.f,0.f,0.f};
    f32x4 s[4];
#pragma unroll
    for (int t = 0; t < 4; ++t) {
      bf16x8 kb = *(const bf16x8*)(kbase + (size_t)(c0 + t * 16 + l15) * 32 + quad * 8);
      s[t] = MFMA16(qa, kb, z, 0, 0, 0);
    }
    float p[4][4];
#pragma unroll
    for (int r = 0; r < 4; ++r) {
      float a0 = __expf(s[0][r]), a1 = __expf(s[1][r]);
      float a2 = __expf(s[2][r]), a3 = __expf(s[3][r]);
      p[0][r] = a0; p[1][r] = a1; p[2][r] = a2; p[3][r] = a3;
      drow[r] += (a0 + a1) + (a2 + a3);
    }
#pragma unroll
    for (int t = 0; t < 4; ++t)
#pragma unroll
      for (int r = 0; r < 4; ++r)
        ps[w][quad * 4 + r][t * 16 + l15] = f2b(p[t][r] - 1.0f);
    asm volatile("s_waitcnt lgkmcnt(0)" ::: "memory");
    const unsigned short* vb0 = vbase + (size_t)(c0 >> 6) * 2048;
#pragma unroll
    for (int kh2 = 0; kh2 < 2; ++kh2) {
      bf16x8 pa = *(const bf16x8*)&ps[w][l15][kh2 * 32 + quad * 8];
#pragma unroll
      for (int dvt = 0; dvt < 2; ++dvt) {
        bf16x8 vb = *(const bf16x8*)(vb0 + (kh2 * 2 + dvt) * 512 + lane * 8);
        oacc[dvt] = MFMA16(pa, vb, oacc[dvt], 0, 0, 0);
      }
    }
  }
  // centering correction: P = (P-1) + 1 -> add quarter column-sum of V once
  const float* vc = vcs + ((b * 4 + half) * 8 + h) * 32;
#pragma unroll
  for (int dvt = 0; dvt < 2; ++dvt) {
    float cs = vc[dvt * 16 + l15];
#pragma unroll
    for (int r = 0; r < 4; ++r) oacc[dvt][r] += cs;
  }
  // denominator reduce across the 16 column-lanes (once per kernel)
#pragma unroll
  for (int r = 0; r < 4; ++r) {
    float sv = drow[r];
    sv += __shfl_xor(sv, 1, 16);
    sv += __shfl_xor(sv, 2, 16);
    sv += __shfl_xor(sv, 4, 16);
    sv += __shfl_xor(sv, 8, 16);
    drow[r] = sv;
  }
  const int lrow = l0 + w * 16 + quad * 4;
  float* poh = po + half * POsz;
#pragma unroll
  for (int r = 0; r < 4; ++r) {
    size_t base = ((size_t)bh * NL + lrow + r) * 32;
    poh[base + l15]      = oacc[0][r];
    poh[base + l15 + 16] = oacc[1][r];
  }
  if (l15 == 0) {
#pragma unroll
    for (int r = 0; r < 4; ++r)
      pd[half * PDsz + (size_t)bh * NL + lrow + r] = drow[r];
  }
}

// ---------- combine 4 n-quarters ----------
__global__ __launch_bounds__(256) void attn_combine(const float* __restrict__ po,
    const float* __restrict__ pd, float* __restrict__ ao)
{
  const size_t POsz = (size_t)32 * NL * 32, PDsz = (size_t)32 * NL;
  int gid = blockIdx.x * 256 + threadIdx.x;        // 2^20
  int dv = gid & 31, l = (gid >> 5) & (NL - 1), h = (gid >> 15) & 7, b = gid >> 18;
  size_t r = ((size_t)(b * 8 + h)) * NL + l;
  float d = pd[r] + pd[PDsz + r] + pd[2 * PDsz + r] + pd[3 * PDsz + r];
  float o = po[r * 32 + dv] + po[POsz + r * 32 + dv]
          + po[2 * POsz + r * 32 + dv] + po[3 * POsz + r * 32 + dv];
  ao[((size_t)(b * NL) + l) * 256 + h * 32 + dv] = o / d;
}

// ---------- f32 NT gemm (proj, precision-critical) ----------
__global__ __launch_bounds__(256) void gemm_nt(const float* __restrict__ A, int lda,
    const float* __restrict__ W, int ldw, const float* __restrict__ bias,
    float* __restrict__ C, int ldc, int K)
{
  __shared__ float As[32][68];
  __shared__ float Ws[32][68];
  const int bm = blockIdx.x * 64, bn = blockIdx.y * 64;
  const int tid = threadIdx.x;
  const int ty = tid >> 4, tx = tid & 15;
  float acc[4][4] = {};
  for (int k0 = 0; k0 < K; k0 += 32) {
#pragma unroll
    for (int it = 0; it < 2; ++it) {
      int c = tid + it * 256;
      int m = c >> 3, kq = (c & 7) << 2;
      float av[4], wv[4];
      load4f(A + (size_t)(bm + m) * lda + k0 + kq, av);
      load4f(W + (size_t)(bn + m) * ldw + k0 + kq, wv);
      As[kq + 0][m] = av[0]; As[kq + 1][m] = av[1]; As[kq + 2][m] = av[2]; As[kq + 3][m] = av[3];
      Ws[kq + 0][m] = wv[0]; Ws[kq + 1][m] = wv[1]; Ws[kq + 2][m] = wv[2]; Ws[kq + 3][m] = wv[3];
    }
    __syncthreads();
#pragma unroll
    for (int kk = 0; kk < 32; ++kk) {
      float a[4], w[4];
      *(float4*)a = *(const float4*)&As[kk][ty << 2];
      *(float4*)w = *(const float4*)&Ws[kk][tx << 2];
#pragma unroll
      for (int i = 0; i < 4; ++i)
#pragma unroll
        for (int j = 0; j < 4; ++j)
          acc[i][j] = fmaf(a[i], w[j], acc[i][j]);
    }
    __syncthreads();
  }
  const int row0 = bm + (ty << 2), col0 = bn + (tx << 2);
  float bb[4];
#pragma unroll
  for (int j = 0; j < 4; ++j) bb[j] = bias[col0 + j];
#pragma unroll
  for (int i = 0; i < 4; ++i) {
    float4 o;
    o.x = acc[i][0] + bb[0]; o.y = acc[i][1] + bb[1];
    o.z = acc[i][2] + bb[2]; o.w = acc[i][3] + bb[3];
    *(float4*)(C + (size_t)(row0 + i) * ldc + col0) = o;
  }
}

// ---------- proj instance-norm ----------
__global__ __launch_bounds__(256) void stats_kernel(const float* __restrict__ X,
    long batchStride, int rowsPerBlock,
    float* __restrict__ sum, float* __restrict__ sumsq)
{
  const int b = blockIdx.x, c = threadIdx.x;
  const long r0 = (long)blockIdx.y * rowsPerBlock;
  const float* base = X + (long)b * batchStride + r0 * 256 + c;
  float s = 0.f, ss = 0.f;
  for (int r = 0; r < rowsPerBlock; ++r) {
    float v = base[(long)r * 256];
    s += v; ss += v * v;
  }
  atomicAdd(&sum[b * 256 + c], s);
  atomicAdd(&sumsq[b * 256 + c], ss);
}

__global__ __launch_bounds__(256) void finalize_stats(const float* __restrict__ sum,
    const float* __restrict__ sumsq, float invR,
    float* __restrict__ mean, float* __restrict__ rstd)
{
  int i = blockIdx.x * 256 + threadIdx.x;
  float m = sum[i] * invR;
  float v = sumsq[i] * invR - m * m;
  mean[i] = m;
  rstd[i] = rsqrtf(v + 1e-5f);
}

__global__ __launch_bounds__(256) void final_out(const float* __restrict__ proj,
    const float* __restrict__ mean, const float* __restrict__ rstd,
    float* __restrict__ out)
{
  const int b = blockIdx.x, o = threadIdx.x;
  const int l1 = blockIdx.y * 16;
  const float m = mean[b * 256 + o], r = rstd[b * 256 + o];
  for (int i = 0; i < 16; ++i) {
    size_t idx = ((size_t)(b * NL + l1 + i)) * 256 + o;
    out[idx] = (proj[idx] - m) * r;
  }
}

extern "C" void kernel_launch(void* const* d_in, const int* in_sizes, int n_in,
                              void* d_out, int out_size, void* d_ws, size_t ws_size,
                              hipStream_t stream)
{
  const float* l  = (const float*)d_in[0];
  const float* x  = (const float*)d_in[1];
  const float* Wq = (const float*)d_in[2];
  const float* bq = (const float*)d_in[3];
  const float* Wk = (const float*)d_in[4];
  const float* bk = (const float*)d_in[5];
  const float* Wv = (const float*)d_in[6];
  const float* bv = (const float*)d_in[7];
  const float* Ww = (const float*)d_in[8];
  const float* bw = (const float*)d_in[9];
  float* out = (float*)d_out;

  unsigned short* up = (unsigned short*)d_ws;
  unsigned short* xbf   = up;                         // 8,388,608
  unsigned short* lbf   = xbf   + 8388608;            // 2,097,152
  unsigned short* wkp   = lbf   + 2097152;            // 131,072
  unsigned short* wvp   = wkp   + 131072;
  unsigned short* wqp   = wvp   + 131072;
  unsigned short* qbuf  = wqp   + 131072;             // 1,048,576
  unsigned short* khb   = qbuf  + 1048576;            // 4,194,304
  unsigned short* vhb   = khb   + 4194304;
  unsigned short* vfrag = vhb   + 4194304;
  // us total = 24,510,464 elements = 49,020,928 bytes
  float* fp    = (float*)((char*)d_ws + 49020928);
  float* krstd = fp;                                  // 1024
  float* vcs   = krstd + 1024;                        // 4096
  float* po    = vcs + 4096;                          // 4 * 1,048,576
  float* pd    = po + 4194304;                        // 4 * 32,768
  float* ao    = pd + 131072;                         // 1,048,576
  float* pj    = ao + 1048576;                        // 1,048,576
  float* st    = pj + 1048576;
  float* psum  = st;        float* psq   = st + 1024;
  float* pmean = st + 2048; float* prstd = st + 3072;

  hipMemsetAsync(st, 0, 2048 * sizeof(float), stream);

  dim3 blk(256);
  conv_bf16<<<8192, blk, 0, stream>>>(x, xbf, 8388608);
  conv_bf16<<<2048, blk, 0, stream>>>(l, lbf, 2097152);
  pack_w<<<dim3(64, 3), blk, 0, stream>>>(Wk, Wv, Wq, wkp, wvp, wqp);
  gemm_qkv<<<640, blk, 0, stream>>>(xbf, lbf, wkp, wvp, wqp, bk, bv, bq, khb, vhb, qbuf);
  kstats<<<32, blk, 0, stream>>>(khb, krstd);
  vsum<<<128, blk, 0, stream>>>(vhb, vcs);
  vpack<<<512, blk, 0, stream>>>(vhb, vfrag);
  attn_mfma<<<dim3(32, 16, 4), blk, 0, stream>>>(qbuf, khb, vfrag, krstd, vcs, po, pd);
  attn_combine<<<4096, blk, 0, stream>>>(po, pd, ao);
  gemm_nt<<<dim3(64, 4), blk, 0, stream>>>(ao, 256, Ww, 256, bw, pj, 256, 256);
  stats_kernel<<<dim3(4, 4), blk, 0, stream>>>(pj, (long)NL * 256, 256, psum, psq);
  finalize_stats<<<4, 256, 0, stream>>>(psum, psq, 1.0f / NL, pmean, prstd);
  final_out<<<dim3(4, 64), blk, 0, stream>>>(pj, pmean, prstd, out);
}

// Round 5
// 269.843 us; speedup vs baseline: 2.9541x; 1.3183x over previous
//
#include <hip/hip_runtime.h>

constexpr int Bn = 4, NL = 1024, HWn = 4096, NH = 8;

typedef __attribute__((ext_vector_type(8))) short bf16x8;
typedef __attribute__((ext_vector_type(4))) float f32x4;
#define MFMA16 __builtin_amdgcn_mfma_f32_16x16x32_bf16

__device__ __forceinline__ float b2f(unsigned short u) {
  union { unsigned int i; float f; } x; x.i = ((unsigned int)u) << 16; return x.f;
}
__device__ __forceinline__ unsigned short f2b(float f) {
  union { float f; unsigned int i; } x; x.f = f;
  unsigned int r = x.i + 0x7fffu + ((x.i >> 16) & 1u);   // RNE
  return (unsigned short)(r >> 16);
}
__device__ __forceinline__ unsigned short f2b_rtz(float f) {
  union { float f; unsigned int i; } x; x.f = f;
  return (unsigned short)(x.i >> 16);
}
__device__ __forceinline__ void load4f(const float* p, float* o) {
  float4 v = *(const float4*)p; o[0] = v.x; o[1] = v.y; o[2] = v.z; o[3] = v.w;
}

// ---------- f32 -> bf16 ----------
__global__ __launch_bounds__(256) void conv_bf16(const float* __restrict__ src,
    unsigned short* __restrict__ dst, int n)
{
  int i = (blockIdx.x * 256 + threadIdx.x) * 4;
  if (i < n) {
    float4 v = *(const float4*)(src + i);
    ushort4 o; o.x = f2b(v.x); o.y = f2b(v.y); o.z = f2b(v.z); o.w = f2b(v.w);
    *(ushort4*)(dst + i) = o;
  }
}

// ---------- unified 128x128 MFMA GEMM (LDS-staged), K=512 ----------
// id<256: K-mat (x@Wk -> khb head-major); id<512: V-mat; id>=512: Q (l@Wq -> qbuf row-major)
__global__ __launch_bounds__(256, 2) void gemm128(
    const unsigned short* __restrict__ xbf, const unsigned short* __restrict__ lbf,
    const unsigned short* __restrict__ wkb, const unsigned short* __restrict__ wvb,
    const unsigned short* __restrict__ wqb,
    const float* __restrict__ bk, const float* __restrict__ bv, const float* __restrict__ bq,
    unsigned short* __restrict__ khb, unsigned short* __restrict__ vhb,
    unsigned short* __restrict__ qbuf)
{
  __shared__ unsigned short As[128 * 32];   // row-major [m][32]
  __shared__ unsigned short Bs[128 * 32];   // row-major [col][32]
  const int id = blockIdx.x;
  const int mode = id < 256 ? 0 : (id < 512 ? 1 : 2);   // 0=K 1=V 2=Q
  const int local = id - (mode == 0 ? 0 : (mode == 1 ? 256 : 512));
  const int rb = local >> 1, cb = local & 1;
  const int m0 = rb * 128, n0 = cb * 128;
  const unsigned short* A = (mode == 2) ? lbf : xbf;
  const unsigned short* W = (mode == 0) ? wkb : (mode == 1 ? wvb : wqb);
  const float* bias = (mode == 0) ? bk : (mode == 1 ? bv : bq);

  const int tid = threadIdx.x, w = tid >> 6, lane = tid & 63;
  const int quad = lane >> 4, l15 = lane & 15;
  const int wr = w >> 1, wc = w & 1;

  // staging piece indices (2 per thread per matrix)
  const int p0 = tid, p1 = tid + 256;
  const int am0 = p0 >> 2, ak0 = (p0 & 3) * 8;
  const int am1 = p1 >> 2, ak1 = (p1 & 3) * 8;

  f32x4 acc[4][4];
#pragma unroll
  for (int i = 0; i < 4; ++i)
#pragma unroll
    for (int j = 0; j < 4; ++j) acc[i][j] = (f32x4){0.f, 0.f, 0.f, 0.f};

  // prefetch kt=0
  bf16x8 ar0 = *(const bf16x8*)(A + (size_t)(m0 + am0) * 512 + ak0);
  bf16x8 ar1 = *(const bf16x8*)(A + (size_t)(m0 + am1) * 512 + ak1);
  bf16x8 br0 = *(const bf16x8*)(W + (size_t)(n0 + am0) * 512 + ak0);
  bf16x8 br1 = *(const bf16x8*)(W + (size_t)(n0 + am1) * 512 + ak1);

  for (int kt = 0; kt < 16; ++kt) {
    __syncthreads();                     // previous iteration's reads done
    *(bf16x8*)&As[p0 * 8] = ar0;
    *(bf16x8*)&As[p1 * 8] = ar1;
    *(bf16x8*)&Bs[p0 * 8] = br0;
    *(bf16x8*)&Bs[p1 * 8] = br1;
    if (kt < 15) {
      int k0 = (kt + 1) * 32;
      ar0 = *(const bf16x8*)(A + (size_t)(m0 + am0) * 512 + k0 + ak0);
      ar1 = *(const bf16x8*)(A + (size_t)(m0 + am1) * 512 + k0 + ak1);
      br0 = *(const bf16x8*)(W + (size_t)(n0 + am0) * 512 + k0 + ak0);
      br1 = *(const bf16x8*)(W + (size_t)(n0 + am1) * 512 + k0 + ak1);
    }
    __syncthreads();
    bf16x8 af[4], bf[4];
#pragma unroll
    for (int fr = 0; fr < 4; ++fr)
      af[fr] = *(const bf16x8*)&As[(wr * 64 + fr * 16 + l15) * 32 + quad * 8];
#pragma unroll
    for (int fc = 0; fc < 4; ++fc)
      bf[fc] = *(const bf16x8*)&Bs[(wc * 64 + fc * 16 + l15) * 32 + quad * 8];
#pragma unroll
    for (int fr = 0; fr < 4; ++fr)
#pragma unroll
      for (int fc = 0; fc < 4; ++fc)
        acc[fr][fc] = MFMA16(af[fr], bf[fc], acc[fr][fc], 0, 0, 0);
  }

  // epilogue
  float bb[4];
#pragma unroll
  for (int fc = 0; fc < 4; ++fc) bb[fc] = bias[n0 + wc * 64 + fc * 16 + l15];
  unsigned short* dst = (mode == 0) ? khb : (mode == 1 ? vhb : qbuf);
#pragma unroll
  for (int fr = 0; fr < 4; ++fr) {
#pragma unroll
    for (int fc = 0; fc < 4; ++fc) {
      int col = n0 + wc * 64 + fc * 16 + l15;
#pragma unroll
      for (int r = 0; r < 4; ++r) {
        int row = m0 + wr * 64 + fr * 16 + quad * 4 + r;
        unsigned short val = f2b(acc[fr][fc][r] + bb[fc]);
        if (mode == 2) {
          dst[(size_t)row * 256 + col] = val;
        } else {
          int b = row >> 12, n = row & 4095, h = col >> 5, d = col & 31;
          dst[((size_t)(b * 8 + h) * 4096 + n) * 32 + d] = val;
        }
      }
    }
  }
}

// ---------- k stats (per b,h,d over n) with atomic partials. grid (32, 8) ----------
__global__ __launch_bounds__(256) void kstats2(const unsigned short* __restrict__ khb,
    float* __restrict__ ksum, float* __restrict__ kss)
{
  const int bh = blockIdx.x, seg = blockIdx.y;
  const int t = threadIdx.x, d = t & 31, g = t >> 5;
  const unsigned short* base = khb + (size_t)bh * 131072 + (size_t)seg * 512 * 32;
  float s = 0.f, ss = 0.f;
  for (int i = 0; i < 64; ++i) {
    float v = b2f(base[(size_t)(g + i * 8) * 32 + d]);
    s += v; ss += v * v;
  }
  __shared__ float rs[256], rss[256];
  rs[t] = s; rss[t] = ss;
  __syncthreads();
  if (t < 32) {
    float a = 0.f, b = 0.f;
    for (int g2 = 0; g2 < 8; ++g2) { a += rs[t + g2 * 32]; b += rss[t + g2 * 32]; }
    atomicAdd(&ksum[bh * 32 + t], a);
    atomicAdd(&kss[bh * 32 + t], b);
  }
}

__global__ __launch_bounds__(256) void kfinal(const float* __restrict__ ksum,
    const float* __restrict__ kss, float* __restrict__ krstd)
{
  int i = blockIdx.x * 256 + threadIdx.x;   // 1024
  float m = ksum[i] * (1.f / 4096.f);
  float var = kss[i] * (1.f / 4096.f) - m * m;
  krstd[i] = rsqrtf(var + 1e-5f);
}

// ---------- V per-eighth column sums. grid (32, 8) -> vcs[seg*1024 + bh*32 + d] ----------
__global__ __launch_bounds__(256) void vsum8(const unsigned short* __restrict__ vhb,
    float* __restrict__ vcs)
{
  const int bh = blockIdx.x, seg = blockIdx.y;
  const int t = threadIdx.x, d = t & 31, g = t >> 5;
  const unsigned short* base = vhb + (size_t)bh * 131072 + (size_t)seg * 512 * 32;
  float s = 0.f;
  for (int i = 0; i < 64; ++i) s += b2f(base[(size_t)(g + i * 8) * 32 + d]);
  __shared__ float rs[256];
  rs[t] = s;
  __syncthreads();
  if (t < 32) {
    float a = 0.f;
    for (int g2 = 0; g2 < 8; ++g2) a += rs[t + g2 * 32];
    vcs[seg * 1024 + bh * 32 + t] = a;
  }
}

// ---------- pack V head-major -> frag-major (verified R4) ----------
__global__ __launch_bounds__(256) void vpack(const unsigned short* __restrict__ vh,
    unsigned short* __restrict__ vfrag)
{
  __shared__ unsigned short vt[256][42];
  const int bh = blockIdx.x >> 4, slab = blockIdx.x & 15;   // 512 blocks
  const unsigned short* src = vh + ((size_t)bh * 4096 + slab * 256) * 32;
  const int t = threadIdx.x;
#pragma unroll
  for (int i = 0; i < 4; ++i) {
    int p = i * 256 + t;
    int n = p >> 2, piece = p & 3;
    uint4 v = *(const uint4*)(src + (size_t)n * 32 + piece * 8);
    unsigned int* lrow = (unsigned int*)&vt[n][piece * 8];
    lrow[0] = v.x; lrow[1] = v.y; lrow[2] = v.z; lrow[3] = v.w;
  }
  __syncthreads();
#pragma unroll
  for (int i = 0; i < 4; ++i) {
    int op = i * 256 + t;
    int lanep = op & 63, rest = op >> 6;
    int dvt = rest & 1, kh2 = (rest >> 1) & 1, chunkl = rest >> 2;
    int lq = lanep >> 4, ll = lanep & 15;
    unsigned short o[8];
#pragma unroll
    for (int j = 0; j < 8; ++j)
      o[j] = vt[chunkl * 64 + kh2 * 32 + lq * 8 + j][dvt * 16 + ll];
    size_t dst = ((((size_t)bh * 64 + slab * 4 + chunkl) * 2 + kh2) * 2 + dvt) * 512 + lanep * 8;
    *(bf16x8*)(vfrag + dst) = *(const bf16x8*)o;
  }
}

// ---------- MFMA flash attention v2: 64-l waves, LDS-shared KV chunks, 8-way n-split ----------
// grid (32, 4, 8) = (bh, lsuper, half); block 256 (4 waves; wave = 64 l-rows)
__global__ __launch_bounds__(256, 3) void attn2(const unsigned short* __restrict__ qbuf,
    const unsigned short* __restrict__ khb, const unsigned short* __restrict__ vfrag,
    const float* __restrict__ krstd, const float* __restrict__ vcs,
    float* __restrict__ po, float* __restrict__ pd)
{
  const int bh = blockIdx.x, b = bh >> 3, h = bh & 7;
  const int lsuper = blockIdx.y, half = blockIdx.z;
  const int tid = threadIdx.x, w = tid >> 6, lane = tid & 63;
  const int quad = lane >> 4, l15 = lane & 15;

  __shared__ unsigned short kb_s[2048];        // [64 n][32 d]
  __shared__ unsigned short vb_s[2048];        // frag-major 4 pieces x 64 lanes x 8
  __shared__ unsigned short ps[4][64][72];     // per-wave P tiles [row l][col n]

  // Q A-frags with krstd * 1/16 folded in (k-mean drops out of softmax)
  bf16x8 qa[4];
  {
    float fold[8];
    const float* rp = krstd + bh * 32 + quad * 8;
#pragma unroll
    for (int j = 0; j < 8; ++j) fold[j] = rp[j] * 0.0625f;
#pragma unroll
    for (int lf = 0; lf < 4; ++lf) {
      int l = lsuper * 256 + w * 64 + lf * 16 + l15;
      bf16x8 qr = *(const bf16x8*)(qbuf + ((size_t)(b * NL + l)) * 256 + h * 32 + quad * 8);
      const unsigned short* qq = (const unsigned short*)&qr;
      unsigned short tmp[8];
#pragma unroll
      for (int j = 0; j < 8; ++j) tmp[j] = f2b(b2f(qq[j]) * fold[j]);
      qa[lf] = *(const bf16x8*)tmp;
    }
  }

  float drow[4][4];
  f32x4 acc[4][2];
#pragma unroll
  for (int lf = 0; lf < 4; ++lf) {
#pragma unroll
    for (int r = 0; r < 4; ++r) drow[lf][r] = 0.f;
    acc[lf][0] = (f32x4){0.f,0.f,0.f,0.f};
    acc[lf][1] = (f32x4){0.f,0.f,0.f,0.f};
  }

  const unsigned short* kcbase = khb + (size_t)bh * 131072 + (size_t)half * 512 * 32;
  const unsigned short* vcbase = vfrag + (size_t)bh * 131072 + (size_t)half * 8 * 2048;

  // prefetch chunk 0
  bf16x8 kreg = *(const bf16x8*)(kcbase + tid * 8);
  bf16x8 vreg = *(const bf16x8*)(vcbase + tid * 8);

  for (int c = 0; c < 8; ++c) {
    __syncthreads();                           // previous chunk's LDS reads done
    *(bf16x8*)&kb_s[tid * 8] = kreg;
    *(bf16x8*)&vb_s[tid * 8] = vreg;
    if (c < 7) {
      kreg = *(const bf16x8*)(kcbase + (c + 1) * 2048 + tid * 8);
      vreg = *(const bf16x8*)(vcbase + (c + 1) * 2048 + tid * 8);
    }
    __syncthreads();

    bf16x8 kb[4];
#pragma unroll
    for (int t = 0; t < 4; ++t)
      kb[t] = *(const bf16x8*)&kb_s[(t * 16 + l15) * 32 + quad * 8];
    bf16x8 vb[4];
#pragma unroll
    for (int i = 0; i < 4; ++i)
      vb[i] = *(const bf16x8*)&vb_s[i * 512 + lane * 8];

    f32x4 z = (f32x4){0.f,0.f,0.f,0.f};
#pragma unroll
    for (int lf = 0; lf < 4; ++lf) {
      f32x4 sv[4];
#pragma unroll
      for (int t = 0; t < 4; ++t) sv[t] = MFMA16(qa[lf], kb[t], z, 0, 0, 0);
#pragma unroll
      for (int r = 0; r < 4; ++r) {
        float e0 = __expf(sv[0][r]), e1 = __expf(sv[1][r]);
        float e2 = __expf(sv[2][r]), e3 = __expf(sv[3][r]);
        drow[lf][r] += (e0 + e1) + (e2 + e3);
        int row = lf * 16 + quad * 4 + r;
        ps[w][row][l15]      = f2b_rtz(e0 - 1.0f);
        ps[w][row][16 + l15] = f2b_rtz(e1 - 1.0f);
        ps[w][row][32 + l15] = f2b_rtz(e2 - 1.0f);
        ps[w][row][48 + l15] = f2b_rtz(e3 - 1.0f);
      }
    }
    asm volatile("s_waitcnt lgkmcnt(0)" ::: "memory");
#pragma unroll
    for (int lf = 0; lf < 4; ++lf) {
#pragma unroll
      for (int kh2 = 0; kh2 < 2; ++kh2) {
        bf16x8 pa = *(const bf16x8*)&ps[w][lf * 16 + l15][kh2 * 32 + quad * 8];
#pragma unroll
        for (int dvt = 0; dvt < 2; ++dvt)
          acc[lf][dvt] = MFMA16(pa, vb[kh2 * 2 + dvt], acc[lf][dvt], 0, 0, 0);
      }
    }
  }

  // centered-P correction: + 1 * (column sum of V over this half's 512 rows)
  const float* vc = vcs + half * 1024 + bh * 32;
  float cs0 = vc[l15], cs1 = vc[16 + l15];
#pragma unroll
  for (int lf = 0; lf < 4; ++lf)
#pragma unroll
    for (int r = 0; r < 4; ++r) {
      acc[lf][0][r] += cs0;
      acc[lf][1][r] += cs1;
    }

  // denominator reduce across 16 column-lanes; write partials
  const size_t PDo = (size_t)half * 32768 + (size_t)bh * 1024;
#pragma unroll
  for (int lf = 0; lf < 4; ++lf) {
#pragma unroll
    for (int r = 0; r < 4; ++r) {
      float sv = drow[lf][r];
      sv += __shfl_xor(sv, 1, 16);
      sv += __shfl_xor(sv, 2, 16);
      sv += __shfl_xor(sv, 4, 16);
      sv += __shfl_xor(sv, 8, 16);
      int l = lsuper * 256 + w * 64 + lf * 16 + quad * 4 + r;
      size_t base = (PDo + l) * 32;
      po[base + l15]      = acc[lf][0][r];
      po[base + 16 + l15] = acc[lf][1][r];
      if (l15 == 0) pd[PDo + l] = sv;
    }
  }
}

// ---------- combine 8 n-eighths ----------
__global__ __launch_bounds__(256) void combine8(const float* __restrict__ po,
    const float* __restrict__ pd, float* __restrict__ ao)
{
  int gid = blockIdx.x * 256 + threadIdx.x;        // 2^20
  int dv = gid & 31, l = (gid >> 5) & (NL - 1), h = (gid >> 15) & 7, b = gid >> 18;
  size_t r = ((size_t)(b * 8 + h)) * 1024 + l;
  float d = 0.f, o = 0.f;
#pragma unroll
  for (int half = 0; half < 8; ++half) {
    size_t rr = (size_t)half * 32768 + r;
    d += pd[rr];
    o += po[rr * 32 + dv];
  }
  ao[((size_t)(b * NL) + l) * 256 + h * 32 + dv] = o / d;
}

// ---------- f32 NT gemm (proj, precision-critical) ----------
__global__ __launch_bounds__(256) void gemm_nt(const float* __restrict__ A, int lda,
    const float* __restrict__ W, int ldw, const float* __restrict__ bias,
    float* __restrict__ C, int ldc, int K)
{
  __shared__ float As[32][68];
  __shared__ float Ws[32][68];
  const int bm = blockIdx.x * 64, bn = blockIdx.y * 64;
  const int tid = threadIdx.x;
  const int ty = tid >> 4, tx = tid & 15;
  float acc[4][4] = {};
  for (int k0 = 0; k0 < K; k0 += 32) {
#pragma unroll
    for (int it = 0; it < 2; ++it) {
      int c = tid + it * 256;
      int m = c >> 3, kq = (c & 7) << 2;
      float av[4], wv[4];
      load4f(A + (size_t)(bm + m) * lda + k0 + kq, av);
      load4f(W + (size_t)(bn + m) * ldw + k0 + kq, wv);
      As[kq + 0][m] = av[0]; As[kq + 1][m] = av[1]; As[kq + 2][m] = av[2]; As[kq + 3][m] = av[3];
      Ws[kq + 0][m] = wv[0]; Ws[kq + 1][m] = wv[1]; Ws[kq + 2][m] = wv[2]; Ws[kq + 3][m] = wv[3];
    }
    __syncthreads();
#pragma unroll
    for (int kk = 0; kk < 32; ++kk) {
      float a[4], w[4];
      *(float4*)a = *(const float4*)&As[kk][ty << 2];
      *(float4*)w = *(const float4*)&Ws[kk][tx << 2];
#pragma unroll
      for (int i = 0; i < 4; ++i)
#pragma unroll
        for (int j = 0; j < 4; ++j)
          acc[i][j] = fmaf(a[i], w[j], acc[i][j]);
    }
    __syncthreads();
  }
  const int row0 = bm + (ty << 2), col0 = bn + (tx << 2);
  float bb[4];
#pragma unroll
  for (int j = 0; j < 4; ++j) bb[j] = bias[col0 + j];
#pragma unroll
  for (int i = 0; i < 4; ++i) {
    float4 o;
    o.x = acc[i][0] + bb[0]; o.y = acc[i][1] + bb[1];
    o.z = acc[i][2] + bb[2]; o.w = acc[i][3] + bb[3];
    *(float4*)(C + (size_t)(row0 + i) * ldc + col0) = o;
  }
}

// ---------- proj instance-norm ----------
__global__ __launch_bounds__(256) void stats_kernel(const float* __restrict__ X,
    long batchStride, int rowsPerBlock,
    float* __restrict__ sum, float* __restrict__ sumsq)
{
  const int b = blockIdx.x, c = threadIdx.x;
  const long r0 = (long)blockIdx.y * rowsPerBlock;
  const float* base = X + (long)b * batchStride + r0 * 256 + c;
  float s = 0.f, ss = 0.f;
  for (int r = 0; r < rowsPerBlock; ++r) {
    float v = base[(long)r * 256];
    s += v; ss += v * v;
  }
  atomicAdd(&sum[b * 256 + c], s);
  atomicAdd(&sumsq[b * 256 + c], ss);
}

__global__ __launch_bounds__(256) void finalize_stats(const float* __restrict__ sum,
    const float* __restrict__ sumsq, float invR,
    float* __restrict__ mean, float* __restrict__ rstd)
{
  int i = blockIdx.x * 256 + threadIdx.x;
  float m = sum[i] * invR;
  float v = sumsq[i] * invR - m * m;
  mean[i] = m;
  rstd[i] = rsqrtf(v + 1e-5f);
}

__global__ __launch_bounds__(256) void final_out(const float* __restrict__ proj,
    const float* __restrict__ mean, const float* __restrict__ rstd,
    float* __restrict__ out)
{
  const int b = blockIdx.x, o = threadIdx.x;
  const int l1 = blockIdx.y * 16;
  const float m = mean[b * 256 + o], r = rstd[b * 256 + o];
  for (int i = 0; i < 16; ++i) {
    size_t idx = ((size_t)(b * NL + l1 + i)) * 256 + o;
    out[idx] = (proj[idx] - m) * r;
  }
}

extern "C" void kernel_launch(void* const* d_in, const int* in_sizes, int n_in,
                              void* d_out, int out_size, void* d_ws, size_t ws_size,
                              hipStream_t stream)
{
  const float* l  = (const float*)d_in[0];
  const float* x  = (const float*)d_in[1];
  const float* Wq = (const float*)d_in[2];
  const float* bq = (const float*)d_in[3];
  const float* Wk = (const float*)d_in[4];
  const float* bk = (const float*)d_in[5];
  const float* Wv = (const float*)d_in[6];
  const float* bv = (const float*)d_in[7];
  const float* Ww = (const float*)d_in[8];
  const float* bw = (const float*)d_in[9];
  float* out = (float*)d_out;

  unsigned short* up = (unsigned short*)d_ws;
  unsigned short* xbf   = up;                         // 8,388,608
  unsigned short* lbf   = xbf   + 8388608;            // 2,097,152
  unsigned short* wkb   = lbf   + 2097152;            // 131,072
  unsigned short* wvb   = wkb   + 131072;
  unsigned short* wqb   = wvb   + 131072;
  unsigned short* qbuf  = wqb   + 131072;             // 1,048,576
  unsigned short* khb   = qbuf  + 1048576;            // 4,194,304
  unsigned short* vhb   = khb   + 4194304;
  unsigned short* vfrag = vhb   + 4194304;
  // ushort total = 24,510,464 -> 49,020,928 bytes
  float* F     = (float*)((char*)d_ws + 49020928);
  float* krstd = F;                                   // 1024
  float* vcs   = krstd + 1024;                        // 8192
  float* po    = vcs + 8192;                          // 8,388,608
  float* pd    = po + 8388608;                        // 262,144
  float* ao    = pd + 262144;                         // 1,048,576
  float* pj    = ao + 1048576;                        // 1,048,576
  float* st    = pj + 1048576;                        // 6144
  float* ksum  = st;          float* kss   = st + 1024;
  float* psum  = st + 2048;   float* psq   = st + 3072;
  float* pmean = st + 4096;   float* prstd = st + 5120;

  hipMemsetAsync(st, 0, 4096 * sizeof(float), stream);

  dim3 blk(256);
  conv_bf16<<<8192, blk, 0, stream>>>(x,  xbf, 8388608);
  conv_bf16<<<2048, blk, 0, stream>>>(l,  lbf, 2097152);
  conv_bf16<<<128,  blk, 0, stream>>>(Wk, wkb, 131072);
  conv_bf16<<<128,  blk, 0, stream>>>(Wv, wvb, 131072);
  conv_bf16<<<128,  blk, 0, stream>>>(Wq, wqb, 131072);
  gemm128<<<576, blk, 0, stream>>>(xbf, lbf, wkb, wvb, wqb, bk, bv, bq, khb, vhb, qbuf);
  kstats2<<<dim3(32, 8), blk, 0, stream>>>(khb, ksum, kss);
  kfinal<<<4, blk, 0, stream>>>(ksum, kss, krstd);
  vsum8<<<dim3(32, 8), blk, 0, stream>>>(vhb, vcs);
  vpack<<<512, blk, 0, stream>>>(vhb, vfrag);
  attn2<<<dim3(32, 4, 8), blk, 0, stream>>>(qbuf, khb, vfrag, krstd, vcs, po, pd);
  combine8<<<4096, blk, 0, stream>>>(po, pd, ao);
  gemm_nt<<<dim3(64, 4), blk, 0, stream>>>(ao, 256, Ww, 256, bw, pj, 256, 256);
  stats_kernel<<<dim3(4, 4), blk, 0, stream>>>(pj, (long)NL * 256, 256, psum, psq);
  finalize_stats<<<4, blk, 0, stream>>>(psum, psq, 1.0f / NL, pmean, prstd);
  final_out<<<dim3(4, 64), blk, 0, stream>>>(pj, pmean, prstd, out);
}

// Round 6
// 209.591 us; speedup vs baseline: 3.8033x; 1.2875x over previous
//
#include <hip/hip_runtime.h>

constexpr int Bn = 4, NL = 1024, HWn = 4096, NH = 8;

typedef __attribute__((ext_vector_type(8))) short bf16x8;
typedef __attribute__((ext_vector_type(4))) float f32x4;
#define MFMA16 __builtin_amdgcn_mfma_f32_16x16x32_bf16

__device__ __forceinline__ float b2f(unsigned short u) {
  union { unsigned int i; float f; } x; x.i = ((unsigned int)u) << 16; return x.f;
}
__device__ __forceinline__ unsigned short f2b(float f) {
  union { float f; unsigned int i; } x; x.f = f;
  unsigned int r = x.i + 0x7fffu + ((x.i >> 16) & 1u);   // RNE
  return (unsigned short)(r >> 16);
}
__device__ __forceinline__ unsigned short f2b_rtz(float f) {
  union { float f; unsigned int i; } x; x.f = f;
  return (unsigned short)(x.i >> 16);
}
__device__ __forceinline__ void load4f(const float* p, float* o) {
  float4 v = *(const float4*)p; o[0] = v.x; o[1] = v.y; o[2] = v.z; o[3] = v.w;
}

// ---------- f32 -> bf16 ----------
__global__ __launch_bounds__(256) void conv_bf16(const float* __restrict__ src,
    unsigned short* __restrict__ dst, int n)
{
  int i = (blockIdx.x * 256 + threadIdx.x) * 4;
  if (i < n) {
    float4 v = *(const float4*)(src + i);
    ushort4 o; o.x = f2b(v.x); o.y = f2b(v.y); o.z = f2b(v.z); o.w = f2b(v.w);
    *(ushort4*)(dst + i) = o;
  }
}

// ---------- 3 weight matrices in one launch. grid (128, 3) ----------
__global__ __launch_bounds__(256) void conv_w3(const float* __restrict__ Wk,
    const float* __restrict__ Wv, const float* __restrict__ Wq,
    unsigned short* __restrict__ wkb, unsigned short* __restrict__ wvb,
    unsigned short* __restrict__ wqb)
{
  const float* src = blockIdx.y == 0 ? Wk : (blockIdx.y == 1 ? Wv : Wq);
  unsigned short* dst = blockIdx.y == 0 ? wkb : (blockIdx.y == 1 ? wvb : wqb);
  int i = (blockIdx.x * 256 + threadIdx.x) * 4;   // n = 131072
  float4 v = *(const float4*)(src + i);
  ushort4 o; o.x = f2b(v.x); o.y = f2b(v.y); o.z = f2b(v.z); o.w = f2b(v.w);
  *(ushort4*)(dst + i) = o;
}

// ---------- unified 128x128 MFMA GEMM (LDS-staged), K=512 ----------
// id<256: K-mat (x@Wk -> khb head-major); id<512: V-mat; id>=512: Q (l@Wq -> qbuf row-major)
__global__ __launch_bounds__(256, 2) void gemm128(
    const unsigned short* __restrict__ xbf, const unsigned short* __restrict__ lbf,
    const unsigned short* __restrict__ wkb, const unsigned short* __restrict__ wvb,
    const unsigned short* __restrict__ wqb,
    const float* __restrict__ bk, const float* __restrict__ bv, const float* __restrict__ bq,
    unsigned short* __restrict__ khb, unsigned short* __restrict__ vhb,
    unsigned short* __restrict__ qbuf)
{
  __shared__ unsigned short As[128 * 32];   // row-major [m][32]
  __shared__ unsigned short Bs[128 * 32];   // row-major [col][32]
  const int id = blockIdx.x;
  const int mode = id < 256 ? 0 : (id < 512 ? 1 : 2);   // 0=K 1=V 2=Q
  const int local = id - (mode == 0 ? 0 : (mode == 1 ? 256 : 512));
  const int rb = local >> 1, cb = local & 1;
  const int m0 = rb * 128, n0 = cb * 128;
  const unsigned short* A = (mode == 2) ? lbf : xbf;
  const unsigned short* W = (mode == 0) ? wkb : (mode == 1 ? wvb : wqb);
  const float* bias = (mode == 0) ? bk : (mode == 1 ? bv : bq);

  const int tid = threadIdx.x, w = tid >> 6, lane = tid & 63;
  const int quad = lane >> 4, l15 = lane & 15;
  const int wr = w >> 1, wc = w & 1;

  const int p0 = tid, p1 = tid + 256;
  const int am0 = p0 >> 2, ak0 = (p0 & 3) * 8;
  const int am1 = p1 >> 2, ak1 = (p1 & 3) * 8;

  f32x4 acc[4][4];
#pragma unroll
  for (int i = 0; i < 4; ++i)
#pragma unroll
    for (int j = 0; j < 4; ++j) acc[i][j] = (f32x4){0.f, 0.f, 0.f, 0.f};

  bf16x8 ar0 = *(const bf16x8*)(A + (size_t)(m0 + am0) * 512 + ak0);
  bf16x8 ar1 = *(const bf16x8*)(A + (size_t)(m0 + am1) * 512 + ak1);
  bf16x8 br0 = *(const bf16x8*)(W + (size_t)(n0 + am0) * 512 + ak0);
  bf16x8 br1 = *(const bf16x8*)(W + (size_t)(n0 + am1) * 512 + ak1);

  for (int kt = 0; kt < 16; ++kt) {
    __syncthreads();
    *(bf16x8*)&As[p0 * 8] = ar0;
    *(bf16x8*)&As[p1 * 8] = ar1;
    *(bf16x8*)&Bs[p0 * 8] = br0;
    *(bf16x8*)&Bs[p1 * 8] = br1;
    if (kt < 15) {
      int k0 = (kt + 1) * 32;
      ar0 = *(const bf16x8*)(A + (size_t)(m0 + am0) * 512 + k0 + ak0);
      ar1 = *(const bf16x8*)(A + (size_t)(m0 + am1) * 512 + k0 + ak1);
      br0 = *(const bf16x8*)(W + (size_t)(n0 + am0) * 512 + k0 + ak0);
      br1 = *(const bf16x8*)(W + (size_t)(n0 + am1) * 512 + k0 + ak1);
    }
    __syncthreads();
    bf16x8 af[4], bf[4];
#pragma unroll
    for (int fr = 0; fr < 4; ++fr)
      af[fr] = *(const bf16x8*)&As[(wr * 64 + fr * 16 + l15) * 32 + quad * 8];
#pragma unroll
    for (int fc = 0; fc < 4; ++fc)
      bf[fc] = *(const bf16x8*)&Bs[(wc * 64 + fc * 16 + l15) * 32 + quad * 8];
#pragma unroll
    for (int fr = 0; fr < 4; ++fr)
#pragma unroll
      for (int fc = 0; fc < 4; ++fc)
        acc[fr][fc] = MFMA16(af[fr], bf[fc], acc[fr][fc], 0, 0, 0);
  }

  float bb[4];
#pragma unroll
  for (int fc = 0; fc < 4; ++fc) bb[fc] = bias[n0 + wc * 64 + fc * 16 + l15];
  unsigned short* dst = (mode == 0) ? khb : (mode == 1 ? vhb : qbuf);
#pragma unroll
  for (int fr = 0; fr < 4; ++fr) {
#pragma unroll
    for (int fc = 0; fc < 4; ++fc) {
      int col = n0 + wc * 64 + fc * 16 + l15;
#pragma unroll
      for (int r = 0; r < 4; ++r) {
        int row = m0 + wr * 64 + fr * 16 + quad * 4 + r;
        unsigned short val = f2b(acc[fr][fc][r] + bb[fc]);
        if (mode == 2) {
          dst[(size_t)row * 256 + col] = val;
        } else {
          int b = row >> 12, n = row & 4095, h = col >> 5, d = col & 31;
          dst[((size_t)(b * 8 + h) * 4096 + n) * 32 + d] = val;
        }
      }
    }
  }
}

// ---------- merged K-stats + V-sums. grid (64, 8): x>>5 selects op, x&31 = bh ----------
__global__ __launch_bounds__(256) void kvstats(const unsigned short* __restrict__ khb,
    const unsigned short* __restrict__ vhb,
    float* __restrict__ ksum, float* __restrict__ kss, float* __restrict__ vcs)
{
  const int which = blockIdx.x >> 5, bh = blockIdx.x & 31, seg = blockIdx.y;
  const int t = threadIdx.x, d = t & 31, g = t >> 5;
  __shared__ float rs[256], rss[256];
  if (which == 0) {
    const unsigned short* base = khb + (size_t)bh * 131072 + (size_t)seg * 512 * 32;
    float s = 0.f, ss = 0.f;
    for (int i = 0; i < 64; ++i) {
      float v = b2f(base[(size_t)(g + i * 8) * 32 + d]);
      s += v; ss += v * v;
    }
    rs[t] = s; rss[t] = ss;
    __syncthreads();
    if (t < 32) {
      float a = 0.f, b = 0.f;
      for (int g2 = 0; g2 < 8; ++g2) { a += rs[t + g2 * 32]; b += rss[t + g2 * 32]; }
      atomicAdd(&ksum[bh * 32 + t], a);
      atomicAdd(&kss[bh * 32 + t], b);
    }
  } else {
    const unsigned short* base = vhb + (size_t)bh * 131072 + (size_t)seg * 512 * 32;
    float s = 0.f;
    for (int i = 0; i < 64; ++i) s += b2f(base[(size_t)(g + i * 8) * 32 + d]);
    rs[t] = s;
    __syncthreads();
    if (t < 32) {
      float a = 0.f;
      for (int g2 = 0; g2 < 8; ++g2) a += rs[t + g2 * 32];
      vcs[seg * 1024 + bh * 32 + t] = a;
    }
  }
}

__global__ __launch_bounds__(256) void kfinal(const float* __restrict__ ksum,
    const float* __restrict__ kss, float* __restrict__ krstd)
{
  int i = blockIdx.x * 256 + threadIdx.x;   // 1024
  float m = ksum[i] * (1.f / 4096.f);
  float var = kss[i] * (1.f / 4096.f) - m * m;
  krstd[i] = rsqrtf(var + 1e-5f);
}

// ---------- pack V head-major -> frag-major ----------
__global__ __launch_bounds__(256) void vpack(const unsigned short* __restrict__ vh,
    unsigned short* __restrict__ vfrag)
{
  __shared__ unsigned short vt[256][42];
  const int bh = blockIdx.x >> 4, slab = blockIdx.x & 15;   // 512 blocks
  const unsigned short* src = vh + ((size_t)bh * 4096 + slab * 256) * 32;
  const int t = threadIdx.x;
#pragma unroll
  for (int i = 0; i < 4; ++i) {
    int p = i * 256 + t;
    int n = p >> 2, piece = p & 3;
    uint4 v = *(const uint4*)(src + (size_t)n * 32 + piece * 8);
    unsigned int* lrow = (unsigned int*)&vt[n][piece * 8];
    lrow[0] = v.x; lrow[1] = v.y; lrow[2] = v.z; lrow[3] = v.w;
  }
  __syncthreads();
#pragma unroll
  for (int i = 0; i < 4; ++i) {
    int op = i * 256 + t;
    int lanep = op & 63, rest = op >> 6;
    int dvt = rest & 1, kh2 = (rest >> 1) & 1, chunkl = rest >> 2;
    int lq = lanep >> 4, ll = lanep & 15;
    unsigned short o[8];
#pragma unroll
    for (int j = 0; j < 8; ++j)
      o[j] = vt[chunkl * 64 + kh2 * 32 + lq * 8 + j][dvt * 16 + ll];
    size_t dst = ((((size_t)bh * 64 + slab * 4 + chunkl) * 2 + kh2) * 2 + dvt) * 512 + lanep * 8;
    *(bf16x8*)(vfrag + dst) = *(const bf16x8*)o;
  }
}

// ---------- MFMA flash attention v2 (verified R5) ----------
// grid (32, 4, 8) = (bh, lsuper, half); block 256 (4 waves; wave = 64 l-rows)
__global__ __launch_bounds__(256, 3) void attn2(const unsigned short* __restrict__ qbuf,
    const unsigned short* __restrict__ khb, const unsigned short* __restrict__ vfrag,
    const float* __restrict__ krstd, const float* __restrict__ vcs,
    float* __restrict__ po, float* __restrict__ pd)
{
  const int bh = blockIdx.x, b = bh >> 3, h = bh & 7;
  const int lsuper = blockIdx.y, half = blockIdx.z;
  const int tid = threadIdx.x, w = tid >> 6, lane = tid & 63;
  const int quad = lane >> 4, l15 = lane & 15;

  __shared__ unsigned short kb_s[2048];
  __shared__ unsigned short vb_s[2048];
  __shared__ unsigned short ps[4][64][72];

  bf16x8 qa[4];
  {
    float fold[8];
    const float* rp = krstd + bh * 32 + quad * 8;
#pragma unroll
    for (int j = 0; j < 8; ++j) fold[j] = rp[j] * 0.0625f;
#pragma unroll
    for (int lf = 0; lf < 4; ++lf) {
      int l = lsuper * 256 + w * 64 + lf * 16 + l15;
      bf16x8 qr = *(const bf16x8*)(qbuf + ((size_t)(b * NL + l)) * 256 + h * 32 + quad * 8);
      const unsigned short* qq = (const unsigned short*)&qr;
      unsigned short tmp[8];
#pragma unroll
      for (int j = 0; j < 8; ++j) tmp[j] = f2b(b2f(qq[j]) * fold[j]);
      qa[lf] = *(const bf16x8*)tmp;
    }
  }

  float drow[4][4];
  f32x4 acc[4][2];
#pragma unroll
  for (int lf = 0; lf < 4; ++lf) {
#pragma unroll
    for (int r = 0; r < 4; ++r) drow[lf][r] = 0.f;
    acc[lf][0] = (f32x4){0.f,0.f,0.f,0.f};
    acc[lf][1] = (f32x4){0.f,0.f,0.f,0.f};
  }

  const unsigned short* kcbase = khb + (size_t)bh * 131072 + (size_t)half * 512 * 32;
  const unsigned short* vcbase = vfrag + (size_t)bh * 131072 + (size_t)half * 8 * 2048;

  bf16x8 kreg = *(const bf16x8*)(kcbase + tid * 8);
  bf16x8 vreg = *(const bf16x8*)(vcbase + tid * 8);

  for (int c = 0; c < 8; ++c) {
    __syncthreads();
    *(bf16x8*)&kb_s[tid * 8] = kreg;
    *(bf16x8*)&vb_s[tid * 8] = vreg;
    if (c < 7) {
      kreg = *(const bf16x8*)(kcbase + (c + 1) * 2048 + tid * 8);
      vreg = *(const bf16x8*)(vcbase + (c + 1) * 2048 + tid * 8);
    }
    __syncthreads();

    bf16x8 kb[4];
#pragma unroll
    for (int t = 0; t < 4; ++t)
      kb[t] = *(const bf16x8*)&kb_s[(t * 16 + l15) * 32 + quad * 8];
    bf16x8 vb[4];
#pragma unroll
    for (int i = 0; i < 4; ++i)
      vb[i] = *(const bf16x8*)&vb_s[i * 512 + lane * 8];

    f32x4 z = (f32x4){0.f,0.f,0.f,0.f};
#pragma unroll
    for (int lf = 0; lf < 4; ++lf) {
      f32x4 sv[4];
#pragma unroll
      for (int t = 0; t < 4; ++t) sv[t] = MFMA16(qa[lf], kb[t], z, 0, 0, 0);
#pragma unroll
      for (int r = 0; r < 4; ++r) {
        float e0 = __expf(sv[0][r]), e1 = __expf(sv[1][r]);
        float e2 = __expf(sv[2][r]), e3 = __expf(sv[3][r]);
        drow[lf][r] += (e0 + e1) + (e2 + e3);
        int row = lf * 16 + quad * 4 + r;
        ps[w][row][l15]      = f2b_rtz(e0 - 1.0f);
        ps[w][row][16 + l15] = f2b_rtz(e1 - 1.0f);
        ps[w][row][32 + l15] = f2b_rtz(e2 - 1.0f);
        ps[w][row][48 + l15] = f2b_rtz(e3 - 1.0f);
      }
    }
    asm volatile("s_waitcnt lgkmcnt(0)" ::: "memory");
#pragma unroll
    for (int lf = 0; lf < 4; ++lf) {
#pragma unroll
      for (int kh2 = 0; kh2 < 2; ++kh2) {
        bf16x8 pa = *(const bf16x8*)&ps[w][lf * 16 + l15][kh2 * 32 + quad * 8];
#pragma unroll
        for (int dvt = 0; dvt < 2; ++dvt)
          acc[lf][dvt] = MFMA16(pa, vb[kh2 * 2 + dvt], acc[lf][dvt], 0, 0, 0);
      }
    }
  }

  const float* vc = vcs + half * 1024 + bh * 32;
  float cs0 = vc[l15], cs1 = vc[16 + l15];
#pragma unroll
  for (int lf = 0; lf < 4; ++lf)
#pragma unroll
    for (int r = 0; r < 4; ++r) {
      acc[lf][0][r] += cs0;
      acc[lf][1][r] += cs1;
    }

  const size_t PDo = (size_t)half * 32768 + (size_t)bh * 1024;
#pragma unroll
  for (int lf = 0; lf < 4; ++lf) {
#pragma unroll
    for (int r = 0; r < 4; ++r) {
      float sv = drow[lf][r];
      sv += __shfl_xor(sv, 1, 16);
      sv += __shfl_xor(sv, 2, 16);
      sv += __shfl_xor(sv, 4, 16);
      sv += __shfl_xor(sv, 8, 16);
      int l = lsuper * 256 + w * 64 + lf * 16 + quad * 4 + r;
      size_t base = (PDo + l) * 32;
      po[base + l15]      = acc[lf][0][r];
      po[base + 16 + l15] = acc[lf][1][r];
      if (l15 == 0) pd[PDo + l] = sv;
    }
  }
}

// ---------- combine 8 n-eighths ----------
__global__ __launch_bounds__(256) void combine8(const float* __restrict__ po,
    const float* __restrict__ pd, float* __restrict__ ao)
{
  int gid = blockIdx.x * 256 + threadIdx.x;
  int dv = gid & 31, l = (gid >> 5) & (NL - 1), h = (gid >> 15) & 7, b = gid >> 18;
  size_t r = ((size_t)(b * 8 + h)) * 1024 + l;
  float d = 0.f, o = 0.f;
#pragma unroll
  for (int half = 0; half < 8; ++half) {
    size_t rr = (size_t)half * 32768 + r;
    d += pd[rr];
    o += po[rr * 32 + dv];
  }
  ao[((size_t)(b * NL) + l) * 256 + h * 32 + dv] = o / d;
}

// ---------- f32 NT gemm (proj, precision-critical) ----------
__global__ __launch_bounds__(256) void gemm_nt(const float* __restrict__ A, int lda,
    const float* __restrict__ W, int ldw, const float* __restrict__ bias,
    float* __restrict__ C, int ldc, int K)
{
  __shared__ float As[32][68];
  __shared__ float Ws[32][68];
  const int bm = blockIdx.x * 64, bn = blockIdx.y * 64;
  const int tid = threadIdx.x;
  const int ty = tid >> 4, tx = tid & 15;
  float acc[4][4] = {};
  for (int k0 = 0; k0 < K; k0 += 32) {
#pragma unroll
    for (int it = 0; it < 2; ++it) {
      int c = tid + it * 256;
      int m = c >> 3, kq = (c & 7) << 2;
      float av[4], wv[4];
      load4f(A + (size_t)(bm + m) * lda + k0 + kq, av);
      load4f(W + (size_t)(bn + m) * ldw + k0 + kq, wv);
      As[kq + 0][m] = av[0]; As[kq + 1][m] = av[1]; As[kq + 2][m] = av[2]; As[kq + 3][m] = av[3];
      Ws[kq + 0][m] = wv[0]; Ws[kq + 1][m] = wv[1]; Ws[kq + 2][m] = wv[2]; Ws[kq + 3][m] = wv[3];
    }
    __syncthreads();
#pragma unroll
    for (int kk = 0; kk < 32; ++kk) {
      float a[4], w[4];
      *(float4*)a = *(const float4*)&As[kk][ty << 2];
      *(float4*)w = *(const float4*)&Ws[kk][tx << 2];
#pragma unroll
      for (int i = 0; i < 4; ++i)
#pragma unroll
        for (int j = 0; j < 4; ++j)
          acc[i][j] = fmaf(a[i], w[j], acc[i][j]);
    }
    __syncthreads();
  }
  const int row0 = bm + (ty << 2), col0 = bn + (tx << 2);
  float bb[4];
#pragma unroll
  for (int j = 0; j < 4; ++j) bb[j] = bias[col0 + j];
#pragma unroll
  for (int i = 0; i < 4; ++i) {
    float4 o;
    o.x = acc[i][0] + bb[0]; o.y = acc[i][1] + bb[1];
    o.z = acc[i][2] + bb[2]; o.w = acc[i][3] + bb[3];
    *(float4*)(C + (size_t)(row0 + i) * ldc + col0) = o;
  }
}

// ---------- proj instance-norm stats. grid (B, 64), 16 rows/block ----------
__global__ __launch_bounds__(256) void stats_kernel(const float* __restrict__ X,
    long batchStride, int rowsPerBlock,
    float* __restrict__ sum, float* __restrict__ sumsq)
{
  const int b = blockIdx.x, c = threadIdx.x;
  const long r0 = (long)blockIdx.y * rowsPerBlock;
  const float* base = X + (long)b * batchStride + r0 * 256 + c;
  float s = 0.f, ss = 0.f;
  for (int r = 0; r < rowsPerBlock; ++r) {
    float v = base[(long)r * 256];
    s += v; ss += v * v;
  }
  atomicAdd(&sum[b * 256 + c], s);
  atomicAdd(&sumsq[b * 256 + c], ss);
}

__global__ __launch_bounds__(256) void finalize_stats(const float* __restrict__ sum,
    const float* __restrict__ sumsq, float invR,
    float* __restrict__ mean, float* __restrict__ rstd)
{
  int i = blockIdx.x * 256 + threadIdx.x;
  float m = sum[i] * invR;
  float v = sumsq[i] * invR - m * m;
  mean[i] = m;
  rstd[i] = rsqrtf(v + 1e-5f);
}

__global__ __launch_bounds__(256) void final_out(const float* __restrict__ proj,
    const float* __restrict__ mean, const float* __restrict__ rstd,
    float* __restrict__ out)
{
  const int b = blockIdx.x, o = threadIdx.x;
  const int l1 = blockIdx.y * 16;
  const float m = mean[b * 256 + o], r = rstd[b * 256 + o];
  for (int i = 0; i < 16; ++i) {
    size_t idx = ((size_t)(b * NL + l1 + i)) * 256 + o;
    out[idx] = (proj[idx] - m) * r;
  }
}

extern "C" void kernel_launch(void* const* d_in, const int* in_sizes, int n_in,
                              void* d_out, int out_size, void* d_ws, size_t ws_size,
                              hipStream_t stream)
{
  const float* l  = (const float*)d_in[0];
  const float* x  = (const float*)d_in[1];
  const float* Wq = (const float*)d_in[2];
  const float* bq = (const float*)d_in[3];
  const float* Wk = (const float*)d_in[4];
  const float* bk = (const float*)d_in[5];
  const float* Wv = (const float*)d_in[6];
  const float* bv = (const float*)d_in[7];
  const float* Ww = (const float*)d_in[8];
  const float* bw = (const float*)d_in[9];
  float* out = (float*)d_out;

  unsigned short* up = (unsigned short*)d_ws;
  unsigned short* xbf   = up;                         // 8,388,608
  unsigned short* lbf   = xbf   + 8388608;            // 2,097,152
  unsigned short* wkb   = lbf   + 2097152;            // 131,072
  unsigned short* wvb   = wkb   + 131072;
  unsigned short* wqb   = wvb   + 131072;
  unsigned short* qbuf  = wqb   + 131072;             // 1,048,576
  unsigned short* khb   = qbuf  + 1048576;            // 4,194,304
  unsigned short* vhb   = khb   + 4194304;
  unsigned short* vfrag = vhb   + 4194304;
  float* F     = (float*)((char*)d_ws + 49020928);
  float* krstd = F;                                   // 1024
  float* vcs   = krstd + 1024;                        // 8192
  float* po    = vcs + 8192;                          // 8,388,608
  float* pd    = po + 8388608;                        // 262,144
  float* ao    = pd + 262144;                         // 1,048,576
  float* pj    = ao + 1048576;                        // 1,048,576
  float* st    = pj + 1048576;                        // 6144
  float* ksum  = st;          float* kss   = st + 1024;
  float* psum  = st + 2048;   float* psq   = st + 3072;
  float* pmean = st + 4096;   float* prstd = st + 5120;

  hipMemsetAsync(st, 0, 4096 * sizeof(float), stream);

  dim3 blk(256);
  conv_bf16<<<8192, blk, 0, stream>>>(x,  xbf, 8388608);
  conv_bf16<<<2048, blk, 0, stream>>>(l,  lbf, 2097152);
  conv_w3<<<dim3(128, 3), blk, 0, stream>>>(Wk, Wv, Wq, wkb, wvb, wqb);
  gemm128<<<576, blk, 0, stream>>>(xbf, lbf, wkb, wvb, wqb, bk, bv, bq, khb, vhb, qbuf);
  kvstats<<<dim3(64, 8), blk, 0, stream>>>(khb, vhb, ksum, kss, vcs);
  kfinal<<<4, blk, 0, stream>>>(ksum, kss, krstd);
  vpack<<<512, blk, 0, stream>>>(vhb, vfrag);
  attn2<<<dim3(32, 4, 8), blk, 0, stream>>>(qbuf, khb, vfrag, krstd, vcs, po, pd);
  combine8<<<4096, blk, 0, stream>>>(po, pd, ao);
  gemm_nt<<<dim3(64, 4), blk, 0, stream>>>(ao, 256, Ww, 256, bw, pj, 256, 256);
  stats_kernel<<<dim3(4, 64), blk, 0, stream>>>(pj, (long)NL * 256, 16, psum, psq);
  finalize_stats<<<4, blk, 0, stream>>>(psum, psq, 1.0f / NL, pmean, prstd);
  final_out<<<dim3(4, 64), blk, 0, stream>>>(pj, pmean, prstd, out);
}